// Round 1
// 723.897 us; speedup vs baseline: 1.0080x; 1.0080x over previous
//
#include <hip/hip_runtime.h>

#define BB 8
#define CIN 64
#define CO 128
#define Hdim 224
#define Wdim 224
#define HWt (224*224)
#define HO 112
#define WO 112
#define Lt (112*112)

typedef unsigned short u16;
typedef short bf16x8 __attribute__((ext_vector_type(8)));
typedef float f32x4  __attribute__((ext_vector_type(4)));
#define MFMA16(a,b,c) __builtin_amdgcn_mfma_f32_16x16x32_bf16((a),(b),(c),0,0,0)

__device__ inline u16 f2bf(float f) {
    union { float f; unsigned u; } v; v.f = f;
    unsigned r = (v.u + 0x7fffu + ((v.u >> 16) & 1u)) >> 16;
    return (u16)r;
}
__device__ inline float bf2f(u16 h) {
    union { unsigned u; float f; } v; v.u = ((unsigned)h) << 16; return v.f;
}
__device__ inline float uasf(unsigned u) {
    union { unsigned u; float f; } v; v.u = u; return v.f;
}
__device__ inline float sum8bf(uint4 v) {
    return bf2f(v.x & 0xffff) + bf2f(v.x >> 16) + bf2f(v.y & 0xffff) + bf2f(v.y >> 16)
         + bf2f(v.z & 0xffff) + bf2f(v.z >> 16) + bf2f(v.w & 0xffff) + bf2f(v.w >> 16);
}

// exact-GELU via Abramowitz-Stegun 7.1.26 erf (max |err| 1.5e-7), ~18 VALU ops
__device__ inline float gelu_fast(float x) {
    float z  = x * 0.7071067811865476f;
    float az = fabsf(z);
    float t  = __builtin_amdgcn_rcpf(fmaf(0.3275911f, az, 1.0f));
    float p  = fmaf(fmaf(fmaf(fmaf(1.061405429f, t, -1.453152027f), t,
                    1.421413741f), t, -0.284496736f), t, 0.254829592f);
    float e  = __expf(-z * z);
    float er = copysignf(1.0f - p * t * e, z);
    return 0.5f * x * (1.0f + er);
}

// ---------------------------------------------------------------------------
// K0: zero a float buffer
// ---------------------------------------------------------------------------
__global__ void zero_kernel(float* __restrict__ p, int n4) {
    int i = blockIdx.x * 256 + threadIdx.x;
    if (i < n4) ((float4*)p)[i] = make_float4(0.f, 0.f, 0.f, 0.f);
}

// ---------------------------------------------------------------------------
// K1: head-specialized depthwise conv (compile-time k) + channel shuffle.
// ---------------------------------------------------------------------------
template<int HEAD>
__global__ __launch_bounds__(256) void dw_conv(
    const float* __restrict__ x, const float* __restrict__ w,
    const float* __restrict__ bias, u16* __restrict__ dwb)
{
    constexpr int K   = 3 + 2*HEAD;
    constexpr int PAD = HEAD + 1;
    constexpr int R   = 32 + 2*PAD;
    const int tile = blockIdx.x;          // 49
    const int c    = blockIdx.y;          // 16
    const int b    = blockIdx.z;          // 8
    const int th = (tile/7)*32, tw = (tile%7)*32;
    __shared__ float patch[R*40];
    const int tid = threadIdx.x;
    const float* xin = x + (size_t)(b*CIN + HEAD*16 + c)*HWt;
    for (int idx = tid; idx < R*40; idx += 256) {
        int r = idx / 40, cc = idx - r*40;
        int gy = th - PAD + r, gx = tw - 4 + cc;
        float v = 0.f;
        if (gy >= 0 && gy < Hdim && gx >= 0 && gx < Wdim) v = xin[gy*Wdim + gx];
        patch[idx] = v;
    }
    float wreg[K*K];
    const float* wp = w + c*K*K;
    #pragma unroll
    for (int i = 0; i < K*K; i++) wreg[i] = wp[i];
    const float bv = bias[c];
    __syncthreads();

    const int ty = tid >> 3, x0 = (tid & 7) * 4;
    float acc[4] = {bv, bv, bv, bv};
    #pragma unroll
    for (int ky = 0; ky < K; ky++) {
        float rr[12];
        *(float4*)&rr[0] = *(const float4*)&patch[(ty+ky)*40 + x0];
        *(float4*)&rr[4] = *(const float4*)&patch[(ty+ky)*40 + x0 + 4];
        *(float4*)&rr[8] = *(const float4*)&patch[(ty+ky)*40 + x0 + 8];
        #pragma unroll
        for (int kx = 0; kx < K; kx++) {
            const float wv = wreg[ky*K + kx];
            #pragma unroll
            for (int j = 0; j < 4; j++)
                acc[j] = fmaf(rr[j + kx + 4 - PAD], wv, acc[j]);
        }
    }
    const int s = c*4 + HEAD;
    u16 o4[4] = {f2bf(acc[0]), f2bf(acc[1]), f2bf(acc[2]), f2bf(acc[3])};
    *(uint2*)&dwb[(size_t)(b*CIN + s)*HWt + (th+ty)*Wdim + tw + x0] = *(uint2*)o4;
}

// ---------------------------------------------------------------------------
// K2: csc 1x1 via MFMA -> y4 space-to-depth parity layout
// ---------------------------------------------------------------------------
__global__ __launch_bounds__(256) void csc_mfma(
    const float* __restrict__ W, const float* __restrict__ bias,
    const u16* __restrict__ dwb, u16* __restrict__ y4)
{
    const int b  = blockIdx.z;
    const int p0 = blockIdx.x * 128;
    __shared__ u16 Abuf[128*72];
    __shared__ u16 Tbuf[32*132];
    const int tid = threadIdx.x;
    const int wv = tid >> 6, ln = tid & 63;
    const int mh = (wv >> 1)*64, nh = (wv & 1)*64;
    const int lm = ln & 15, kq = ln >> 4;
    for (int t = tid; t < 1024; t += 256) {
        int r = t >> 3, kk = (t & 7)*8;
        const float* src = &W[r*64 + kk];
        float4 f0 = *(const float4*)src, f1 = *(const float4*)(src+4);
        u16 tmp[8] = {f2bf(f0.x),f2bf(f0.y),f2bf(f0.z),f2bf(f0.w),
                      f2bf(f1.x),f2bf(f1.y),f2bf(f1.z),f2bf(f1.w)};
        *(uint4*)&Abuf[r*72 + kk] = *(uint4*)tmp;
    }
    const u16* Db = dwb + (size_t)b*CIN*HWt;
    f32x4 acc[4][4];
    #pragma unroll
    for (int i=0;i<4;i++)
        #pragma unroll
        for (int j=0;j<4;j++) acc[i][j] = (f32x4){0.f,0.f,0.f,0.f};

    for (int kc = 0; kc < 64; kc += 32) {
        __syncthreads();
        for (int t = tid; t < 512; t += 256) {
            int k = t >> 4, n0 = (t & 15)*8;
            *(uint4*)&Tbuf[k*132 + n0] = *(const uint4*)&Db[(size_t)(kc+k)*HWt + p0 + n0];
        }
        __syncthreads();
        bf16x8 af[4], bfr[4];
        #pragma unroll
        for (int tm=0;tm<4;tm++)
            af[tm] = *(bf16x8*)&Abuf[(mh + tm*16 + lm)*72 + kc + kq*8];
        #pragma unroll
        for (int tn=0;tn<4;tn++) {
            int n = nh + tn*16 + lm;
            #pragma unroll
            for (int j=0;j<8;j++) bfr[tn][j] = (short)Tbuf[(kq*8+j)*132 + n];
        }
        #pragma unroll
        for (int tm=0;tm<4;tm++)
            #pragma unroll
            for (int tn=0;tn<4;tn++)
                acc[tm][tn] = MFMA16(af[tm], bfr[tn], acc[tm][tn]);
    }
    #pragma unroll
    for (int tm=0;tm<4;tm++) {
        #pragma unroll
        for (int r=0;r<4;r++) {
            int o = mh + tm*16 + kq*4 + r;
            float bb = bias[o];
            #pragma unroll
            for (int tn=0;tn<4;tn++) {
                int p = p0 + nh + tn*16 + lm;
                int gy = p / 224, gx = p - gy*224;
                int w = (gy&1)*2 + (gx&1);
                y4[((size_t)(b*CO + o)*4 + w)*Lt + (gy>>1)*WO + (gx>>1)]
                    = f2bf(acc[tm][tn][r] + bb);
            }
        }
    }
}

// ---------------------------------------------------------------------------
// K3: BN(eval) -> exact GELU -> dw conv k=7 s=2  (y4 -> gbf)
// Rewritten: f32 LDS patch (BN+GELU applied once per staged pixel, parity
// planes de-interleaved to row-major), register-tiled conv (8 outputs/thread,
// 6x ds_read_b128 + 56 FMA per ky), skewed LDS rows for conflict-free b128.
// Tile: 16 out-rows x 112 out-cols per block, exact cover (grid 7 x 128 x 8).
// ---------------------------------------------------------------------------
__global__ __launch_bounds__(256) void ggm_kernel(const u16* __restrict__ y4,
    const float* __restrict__ gamma, const float* __restrict__ beta,
    const float* __restrict__ mean, const float* __restrict__ var,
    const float* __restrict__ gw, const float* __restrict__ gb,
    u16* __restrict__ gbf)
{
    const int ho0 = blockIdx.x * 16;      // 7 tiles, exact
    const int c   = blockIdx.y;           // 128
    const int b   = blockIdx.z;           // 8
    // rows: 37 input rows (gy = 2*ho0-3 .. 2*ho0+33)
    // content col j <-> gx = j-8 ; content width 240 (gx -8..231), pads zeroed
    // row r lives at float offset r*272 + 4*((r>>1)&7)   (skew kills conflicts)
    __shared__ float patch[37*272];
    const int tid = threadIdx.x;

    const float inv = gamma[c] * rsqrtf(var[c] + 1e-5f);
    const float bsh = fmaf(-mean[c], inv, beta[c]);
    const u16* ybc = y4 + (size_t)(b*CO + c)*4*Lt;

    // ---- stage: de-interleave parity planes, BN+GELU, write f32 ----
    for (int idx = tid; idx < 37*14; idx += 256) {
        int r = idx / 14, q = idx - r*14;           // segment q: gx 16q..16q+15
        int gy = 2*ho0 - 3 + r;
        float* dst = &patch[r*272 + 4*((r>>1)&7) + 8 + 16*q];
        if (gy >= 0 && gy < Hdim) {
            // even-gx plane (px=0) and odd-gx plane (px=1) for this row parity
            const u16* pe = ybc + (size_t)((gy&1)*2)*Lt + (gy>>1)*WO + 8*q;
            uint4 ve = *(const uint4*)pe;           // 8 even-gx bf16
            uint4 vo = *(const uint4*)(pe + Lt);    // 8 odd-gx bf16
            unsigned eu[4] = {ve.x, ve.y, ve.z, ve.w};
            unsigned ou[4] = {vo.x, vo.y, vo.z, vo.w};
            float o[16];
            #pragma unroll
            for (int i = 0; i < 4; i++) {
                float e0 = uasf(eu[i] << 16), e1 = uasf(eu[i] & 0xffff0000u);
                float d0 = uasf(ou[i] << 16), d1 = uasf(ou[i] & 0xffff0000u);
                o[4*i+0] = gelu_fast(fmaf(e0, inv, bsh));
                o[4*i+1] = gelu_fast(fmaf(d0, inv, bsh));
                o[4*i+2] = gelu_fast(fmaf(e1, inv, bsh));
                o[4*i+3] = gelu_fast(fmaf(d1, inv, bsh));
            }
            #pragma unroll
            for (int i = 0; i < 4; i++)
                *(float4*)&dst[4*i] = *(float4*)&o[4*i];
        } else {
            float4 z = make_float4(0.f,0.f,0.f,0.f);
            #pragma unroll
            for (int i = 0; i < 4; i++) *(float4*)&dst[4*i] = z;
        }
    }
    // zero pads: content cols 0..7 (gx -8..-1) and 232..239 (gx 224..231)
    for (int idx = tid; idx < 37*2; idx += 256) {
        int r = idx >> 1, side = idx & 1;
        float* dst = &patch[r*272 + 4*((r>>1)&7) + (side ? 232 : 0)];
        float4 z = make_float4(0.f,0.f,0.f,0.f);
        *(float4*)&dst[0] = z; *(float4*)&dst[4] = z;
    }
    // weights: uniform per block -> SGPRs
    float wk[49];
    const float* wp = gw + c*49;
    #pragma unroll
    for (int i = 0; i < 49; i++) wk[i] = wp[i];
    const float bv = gb[c];
    __syncthreads();

    // ---- conv: each thread -> 8-wide output strip ----
    const int ty = tid >> 4, m = tid & 15;      // row ho0+ty, cols 8m..8m+7
    if (m < 14) {
        float acc[8] = {bv,bv,bv,bv,bv,bv,bv,bv};
        #pragma unroll
        for (int ky = 0; ky < 7; ky++) {
            int r = 2*ty + ky;
            // window start content col 16m+4  (gx = 16m-4); need offs 1..21
            const float* row = &patch[r*272 + 4*((r>>1)&7) + 16*m + 4];
            float f[24];
            #pragma unroll
            for (int u = 0; u < 6; u++)
                *(float4*)&f[4*u] = *(const float4*)&row[4*u];
            #pragma unroll
            for (int kx = 0; kx < 7; kx++) {
                const float wv = wk[ky*7 + kx];
                #pragma unroll
                for (int j = 0; j < 8; j++)
                    acc[j] = fmaf(f[2*j + kx + 1], wv, acc[j]);
            }
        }
        u16 o8[8];
        #pragma unroll
        for (int j = 0; j < 8; j++) o8[j] = f2bf(acc[j]);
        *(uint4*)&gbf[(size_t)(b*CO + c)*Lt + (ho0 + ty)*WO + 8*m] = *(uint4*)o8;
    }
}

// ---------------------------------------------------------------------------
// K4: G_p[b,c2,c'] = sum_l g[c2,l]*tok_p[c',l] via MFMA, split-K atomics.
// ---------------------------------------------------------------------------
__global__ __launch_bounds__(256) void G_mfma(
    const u16* __restrict__ gbf, const u16* __restrict__ y4,
    float* __restrict__ G)
{
    const int b = blockIdx.z, p = blockIdx.y, split = blockIdx.x;  // (32,5,8)
    const u16* Ab = gbf + (size_t)b*CO*Lt;
    const u16* Bb; int brs;
    if (p == 0) { Bb = Ab; brs = Lt; }
    else        { Bb = y4 + ((size_t)b*CO*4 + (p-1))*Lt; brs = 4*Lt; }
    __shared__ u16 Abuf[128*40];
    __shared__ u16 Bbuf[128*40];
    const int tid = threadIdx.x;
    const int wv = tid >> 6, ln = tid & 63;
    const int mh = (wv >> 1)*64, nh = (wv & 1)*64;
    const int lm = ln & 15, kq = ln >> 4;
    f32x4 acc[4][4];
    #pragma unroll
    for (int i=0;i<4;i++)
        #pragma unroll
        for (int j=0;j<4;j++) acc[i][j] = (f32x4){0.f,0.f,0.f,0.f};

    for (int ci = split; ci < 392; ci += 32) {
        const int l0 = ci*32;
        __syncthreads();
        for (int t = tid; t < 512; t += 256) {
            int r = t >> 2, kk = (t & 3)*8;
            *(uint4*)&Abuf[r*40 + kk] = *(const uint4*)&Ab[(size_t)r*Lt  + l0 + kk];
            *(uint4*)&Bbuf[r*40 + kk] = *(const uint4*)&Bb[(size_t)r*brs + l0 + kk];
        }
        __syncthreads();
        bf16x8 af[4], bfr[4];
        #pragma unroll
        for (int tm=0;tm<4;tm++)
            af[tm]  = *(bf16x8*)&Abuf[(mh + tm*16 + lm)*40 + kq*8];
        #pragma unroll
        for (int tn=0;tn<4;tn++)
            bfr[tn] = *(bf16x8*)&Bbuf[(nh + tn*16 + lm)*40 + kq*8];
        #pragma unroll
        for (int tm=0;tm<4;tm++)
            #pragma unroll
            for (int tn=0;tn<4;tn++)
                acc[tm][tn] = MFMA16(af[tm], bfr[tn], acc[tm][tn]);
    }
    float* Go = G + ((size_t)(b*5 + p))*CO*CO;
    #pragma unroll
    for (int tm=0;tm<4;tm++)
        #pragma unroll
        for (int r=0;r<4;r++) {
            int mrow = mh + tm*16 + kq*4 + r;
            #pragma unroll
            for (int tn=0;tn<4;tn++)
                atomicAdd(&Go[mrow*CO + nh + tn*16 + lm], acc[tm][tn][r]);
        }
}

// ---------------------------------------------------------------------------
// K5: S_p[b,c'] column sums (p=0: g; p=1..4: y4 parity rows)
// ---------------------------------------------------------------------------
__global__ void S_kernel(const u16* __restrict__ gbf, const u16* __restrict__ y4,
                         float* __restrict__ S)
{
    const int b = blockIdx.x >> 7, c = blockIdx.x & 127;
    const u16* gr = gbf + (size_t)(b*CO+c)*Lt;
    const u16* yr = y4  + (size_t)(b*CO+c)*4*Lt;
    float vals[5] = {0.f,0.f,0.f,0.f,0.f};
    for (int i = threadIdx.x*8; i < Lt; i += 256*8)
        vals[0] += sum8bf(*(const uint4*)&gr[i]);
    #pragma unroll
    for (int w=0; w<4; w++)
        for (int i = threadIdx.x*8; i < Lt; i += 256*8)
            vals[1+w] += sum8bf(*(const uint4*)&yr[(size_t)w*Lt + i]);
    #pragma unroll
    for (int off=32; off>0; off>>=1) {
        #pragma unroll
        for (int q=0;q<5;q++) vals[q] += __shfl_down(vals[q], off);
    }
    __shared__ float red[4][5];
    const int wid = threadIdx.x>>6, lane = threadIdx.x&63;
    if (lane==0) {
        #pragma unroll
        for (int q=0;q<5;q++) red[wid][q] = vals[q];
    }
    __syncthreads();
    if (threadIdx.x==0) {
        #pragma unroll
        for (int q=0;q<5;q++)
            S[((size_t)b*5 + q)*CO + c] = red[0][q]+red[1][q]+red[2][q]+red[3][q];
    }
}

// ---------------------------------------------------------------------------
// K6: fused KG+logits per (b,p).  KG_p = G_p · kw^T computed as a register-
// tiled fp32 GEMM (KG never leaves LDS), then lanes 0..127 finish
// lg[b,p,c] = qb*ks_p + kb*sq + sum_c2 Qw[c,c2]*KG[c2,c].
// ---------------------------------------------------------------------------
__global__ __launch_bounds__(256) void fused_logits_kernel(
    const float* __restrict__ G, const float* __restrict__ S,
    const float* __restrict__ qkv_w, const float* __restrict__ qkv_b,
    float* __restrict__ lg)
{
    const int p = blockIdx.x, b = blockIdx.y;   // grid (5,8)
    __shared__ float Wl[32*132];                // G chunk, transposed [kk][c2]
    __shared__ float Al[32*132];                // kw^T chunk [kk][c]
    __shared__ float KGl[128*128];              // KG[c2][c]
    const int tid = threadIdx.x;
    const int og = (tid >> 4) * 8;              // c2 tile
    const int pg = (tid & 15) * 8;              // c tile
    const float* Gp = G + (size_t)(b*5 + p)*CO*CO;
    float acc[8][8];
    #pragma unroll
    for (int i=0;i<8;i++)
        #pragma unroll
        for (int j=0;j<8;j++) acc[i][j]=0.f;

    for (int kc = 0; kc < 128; kc += 32) {
        __syncthreads();
        for (int t = tid; t < 4096; t += 256) {
            int kk = t & 31, o = t >> 5;
            Wl[kk*132 + o] = Gp[(size_t)o*CO + kc + kk];          // G[c2][cp]
            Al[kk*132 + o] = qkv_w[(size_t)(CO + o)*CO + kc + kk]; // kw[c][cp]
        }
        __syncthreads();
        #pragma unroll 4
        for (int kk = 0; kk < 32; kk++) {
            float wv[8], av[8];
            *(float4*)&wv[0] = *(const float4*)&Wl[kk*132+og];
            *(float4*)&wv[4] = *(const float4*)&Wl[kk*132+og+4];
            *(float4*)&av[0] = *(const float4*)&Al[kk*132+pg];
            *(float4*)&av[4] = *(const float4*)&Al[kk*132+pg+4];
            #pragma unroll
            for (int i=0;i<8;i++)
                #pragma unroll
                for (int j=0;j<8;j++)
                    acc[i][j] = fmaf(wv[i], av[j], acc[i][j]);
        }
    }
    // KG tile -> LDS
    #pragma unroll
    for (int i=0;i<8;i++) {
        #pragma unroll
        for (int j=0;j<8;j+=4)
            *(float4*)&KGl[(og+i)*128 + pg + j] = *(float4*)&acc[i][j];
    }
    __syncthreads();
    if (tid < 128) {
        const int c = tid;
        const float qb = qkv_b[c], kb = qkv_b[CO + c];
        const float* S0 = S + (size_t)b*5*CO;        // g-token sums
        const float* Sp = S0 + p*CO;                 // token-p sums
        const float* qwrow = qkv_w + (size_t)c*CO;
        const float* kwrow = qkv_w + (size_t)(CO + c)*CO;
        float sq = qb * 12544.f, ks = 0.f, s = 0.f;
        for (int c2 = 0; c2 < CO; c2++) {
            sq = fmaf(qwrow[c2], S0[c2], sq);
            ks = fmaf(kwrow[c2], Sp[c2], ks);
            s  = fmaf(qwrow[c2], KGl[c2*128 + c], s);
        }
        lg[(size_t)(b*5 + p)*CO + c] = s + qb*ks + kb*sq;
    }
}

// ---------------------------------------------------------------------------
// K7: 5-way softmax over p -> a[b,c,p]
// ---------------------------------------------------------------------------
__global__ void softmax5_kernel(const float* __restrict__ lg, float* __restrict__ a)
{
    const int b = blockIdx.x, c = threadIdx.x;  // grid 8 x 128
    float v[5];
    #pragma unroll
    for (int p=0;p<5;p++) v[p] = lg[(size_t)(b*5 + p)*CO + c];
    const float scl = 0.08838834764831845f; // 1/sqrt(128)
    float mx = v[0];
    #pragma unroll
    for (int p=1;p<5;p++) mx = fmaxf(mx, v[p]);
    float e[5], sum = 0.f;
    #pragma unroll
    for (int p=0;p<5;p++){ e[p] = __expf((v[p]-mx)*scl); sum += e[p]; }
    const float rs = 1.f/sum;
    #pragma unroll
    for (int p=0;p<5;p++) a[((size_t)b*CO + c)*5 + p] = e[p]*rs;
}

// ---------------------------------------------------------------------------
// K8: F_p[b,o,c'] = sum_c proj_w[o,c]*a[b,c,p]*Vw[c,c']   (fp32)
// ---------------------------------------------------------------------------
__global__ void F_kernel(const float* __restrict__ proj_w,
    const float* __restrict__ qkv_w, const float* __restrict__ a,
    float* __restrict__ F)
{
    const int b = blockIdx.z, p = blockIdx.y;   // (64,5,8) x 256
    const int o  = blockIdx.x*2 + (threadIdx.x>>7);
    const int cp = threadIdx.x & 127;
    const float* vw = qkv_w + 2*CO*CO;
    float s = 0.f;
    for (int c=0;c<CO;c++)
        s = fmaf(proj_w[o*CO+c] * a[((size_t)b*CO+c)*5 + p], vw[c*CO+cp], s);
    F[(((size_t)(b*5+p))*CO + o)*CO + cp] = s;
}

// ---------------------------------------------------------------------------
// K9: biasout[o] = proj_b[o] + sum_c proj_w[o,c]*vb[c]
// ---------------------------------------------------------------------------
__global__ void bias_kernel(const float* __restrict__ proj_w,
    const float* __restrict__ proj_b, const float* __restrict__ qkv_b,
    float* __restrict__ biasout)
{
    const int o = threadIdx.x; // 128
    const float* vb = qkv_b + 2*CO;
    float s = proj_b[o];
    for (int c=0;c<CO;c++) s = fmaf(proj_w[o*CO+c], vb[c], s);
    biasout[o] = s;
}

// ---------------------------------------------------------------------------
// K10: out[b,o,l] = sum_p F_p[o,:]·tok_p[:,l] + biasout[o]  via MFMA
// ---------------------------------------------------------------------------
__global__ __launch_bounds__(256) void final_mfma(
    const float* __restrict__ F, const u16* __restrict__ gbf,
    const u16* __restrict__ y4, const float* __restrict__ biasout,
    float* __restrict__ out)
{
    const int b = blockIdx.z;
    const int p0 = blockIdx.x * 128;
    __shared__ u16 Abuf[128*40];
    __shared__ u16 Tbuf[32*132];
    const int tid = threadIdx.x;
    const int wv = tid >> 6, ln = tid & 63;
    const int mh = (wv >> 1)*64, nh = (wv & 1)*64;
    const int lm = ln & 15, kq = ln >> 4;
    f32x4 acc[4][4];
    #pragma unroll
    for (int i=0;i<4;i++)
        #pragma unroll
        for (int j=0;j<4;j++) acc[i][j] = (f32x4){0.f,0.f,0.f,0.f};

    for (int ph = 0; ph < 5; ph++) {
        const float* Fp = F + (size_t)(b*5 + ph)*CO*CO;
        const u16* Bb; int brs;
        if (ph == 0) { Bb = gbf + (size_t)b*CO*Lt; brs = Lt; }
        else         { Bb = y4 + ((size_t)b*CO*4 + (ph-1))*Lt; brs = 4*Lt; }
        for (int kc = 0; kc < CO; kc += 32) {
            __syncthreads();
            for (int t = tid; t < 512; t += 256) {
                int r = t >> 2, kk = (t & 3)*8;
                const float* src = &Fp[r*CO + kc + kk];
                float4 f0 = *(const float4*)src, f1 = *(const float4*)(src+4);
                u16 tmp[8] = {f2bf(f0.x),f2bf(f0.y),f2bf(f0.z),f2bf(f0.w),
                              f2bf(f1.x),f2bf(f1.y),f2bf(f1.z),f2bf(f1.w)};
                *(uint4*)&Abuf[r*40 + kk] = *(uint4*)tmp;
            }
            for (int t = tid; t < 512; t += 256) {
                int k = t >> 4, n0 = (t & 15)*8;
                *(uint4*)&Tbuf[k*132 + n0] = *(const uint4*)&Bb[(size_t)(kc+k)*brs + p0 + n0];
            }
            __syncthreads();
            bf16x8 af[4], bfr[4];
            #pragma unroll
            for (int tm=0;tm<4;tm++)
                af[tm] = *(bf16x8*)&Abuf[(mh + tm*16 + lm)*40 + kq*8];
            #pragma unroll
            for (int tn=0;tn<4;tn++) {
                int n = nh + tn*16 + lm;
                #pragma unroll
                for (int j=0;j<8;j++) bfr[tn][j] = (short)Tbuf[(kq*8+j)*132 + n];
            }
            #pragma unroll
            for (int tm=0;tm<4;tm++)
                #pragma unroll
                for (int tn=0;tn<4;tn++)
                    acc[tm][tn] = MFMA16(af[tm], bfr[tn], acc[tm][tn]);
        }
    }
    float* Ob = out + (size_t)b*CO*Lt;
    #pragma unroll
    for (int tm=0;tm<4;tm++) {
        #pragma unroll
        for (int r=0;r<4;r++) {
            int o = mh + tm*16 + kq*4 + r;
            float bb = biasout[o];
            #pragma unroll
            for (int tn=0;tn<4;tn++)
                Ob[(size_t)o*Lt + p0 + nh + tn*16 + lm] = acc[tm][tn][r] + bb;
        }
    }
}

// ---------------------------------------------------------------------------
extern "C" void kernel_launch(void* const* d_in, const int* in_sizes, int n_in,
                              void* d_out, int out_size, void* d_ws, size_t ws_size,
                              hipStream_t stream) {
    const float* x      = (const float*)d_in[0];
    const float* dw_w0  = (const float*)d_in[1];
    const float* dw_b0  = (const float*)d_in[2];
    const float* dw_w1  = (const float*)d_in[3];
    const float* dw_b1  = (const float*)d_in[4];
    const float* dw_w2  = (const float*)d_in[5];
    const float* dw_b2  = (const float*)d_in[6];
    const float* dw_w3  = (const float*)d_in[7];
    const float* dw_b3  = (const float*)d_in[8];
    const float* csc_w  = (const float*)d_in[9];
    const float* csc_b  = (const float*)d_in[10];
    const float* bn_g   = (const float*)d_in[11];
    const float* bn_b   = (const float*)d_in[12];
    const float* bn_m   = (const float*)d_in[13];
    const float* bn_v   = (const float*)d_in[14];
    const float* ggm_w  = (const float*)d_in[15];
    const float* ggm_b  = (const float*)d_in[16];
    const float* qkv_w  = (const float*)d_in[17];
    const float* qkv_b  = (const float*)d_in[18];
    const float* proj_w = (const float*)d_in[19];
    const float* proj_b = (const float*)d_in[20];
    float* out = (float*)d_out;

    // workspace layout (bytes; all 16B-aligned)
    char* ws = (char*)d_ws;
    u16*   y4  = (u16*)(ws);                          // 102,760,448 B
    u16*   dwb = (u16*)(ws + 102760448);              //  51,380,224 B
    u16*   gbf = (u16*)(ws + 154140672);              //  25,690,112 B
    float* G   = (float*)(ws + 179830784);            // 655,360 f32
    float* lgb = G  + 655360;                         // 5,120
    float* F   = lgb + 5120;                          // 655,360
    float* S   = F  + 655360;                         // 5,120
    float* aw  = S  + 5120;                           // 5,120
    float* bo  = aw + 5120;                           // 128

    zero_kernel<<<dim3(640), 256, 0, stream>>>(G, 655360/4);

    dw_conv<0><<<dim3(49, 16, 8), 256, 0, stream>>>(x, dw_w0, dw_b0, dwb);
    dw_conv<1><<<dim3(49, 16, 8), 256, 0, stream>>>(x, dw_w1, dw_b1, dwb);
    dw_conv<2><<<dim3(49, 16, 8), 256, 0, stream>>>(x, dw_w2, dw_b2, dwb);
    dw_conv<3><<<dim3(49, 16, 8), 256, 0, stream>>>(x, dw_w3, dw_b3, dwb);

    csc_mfma<<<dim3(392, 1, 8), 256, 0, stream>>>(csc_w, csc_b, dwb, y4);

    ggm_kernel<<<dim3(7, 128, 8), 256, 0, stream>>>(
        y4, bn_g, bn_b, bn_m, bn_v, ggm_w, ggm_b, gbf);

    G_mfma<<<dim3(32, 5, 8), 256, 0, stream>>>(gbf, y4, G);

    S_kernel<<<dim3(1024), 256, 0, stream>>>(gbf, y4, S);

    fused_logits_kernel<<<dim3(5, 8), 256, 0, stream>>>(G, S, qkv_w, qkv_b, lgb);

    softmax5_kernel<<<dim3(8), 128, 0, stream>>>(lgb, aw);

    F_kernel<<<dim3(64, 5, 8), 256, 0, stream>>>(proj_w, qkv_w, aw, F);
    bias_kernel<<<dim3(1), 128, 0, stream>>>(proj_w, proj_b, qkv_b, bo);

    final_mfma<<<dim3(98, 1, 8), 256, 0, stream>>>(F, gbf, y4, bo, out);
}

// Round 2
// 693.816 us; speedup vs baseline: 1.0518x; 1.0434x over previous
//
#include <hip/hip_runtime.h>

#define BB 8
#define CIN 64
#define CO 128
#define Hdim 224
#define Wdim 224
#define HWt (224*224)
#define HO 112
#define WO 112
#define Lt (112*112)

typedef unsigned short u16;
typedef short bf16x8 __attribute__((ext_vector_type(8)));
typedef float f32x4  __attribute__((ext_vector_type(4)));
#define MFMA16(a,b,c) __builtin_amdgcn_mfma_f32_16x16x32_bf16((a),(b),(c),0,0,0)

__device__ inline u16 f2bf(float f) {
    union { float f; unsigned u; } v; v.f = f;
    unsigned r = (v.u + 0x7fffu + ((v.u >> 16) & 1u)) >> 16;
    return (u16)r;
}
__device__ inline float bf2f(u16 h) {
    union { unsigned u; float f; } v; v.u = ((unsigned)h) << 16; return v.f;
}
__device__ inline float uasf(unsigned u) {
    union { unsigned u; float f; } v; v.u = u; return v.f;
}
__device__ inline float sum8bf(uint4 v) {
    return bf2f(v.x & 0xffff) + bf2f(v.x >> 16) + bf2f(v.y & 0xffff) + bf2f(v.y >> 16)
         + bf2f(v.z & 0xffff) + bf2f(v.z >> 16) + bf2f(v.w & 0xffff) + bf2f(v.w >> 16);
}

// exact-GELU via Abramowitz-Stegun 7.1.26 erf (max |err| 1.5e-7), ~18 VALU ops
__device__ inline float gelu_fast(float x) {
    float z  = x * 0.7071067811865476f;
    float az = fabsf(z);
    float t  = __builtin_amdgcn_rcpf(fmaf(0.3275911f, az, 1.0f));
    float p  = fmaf(fmaf(fmaf(fmaf(1.061405429f, t, -1.453152027f), t,
                    1.421413741f), t, -0.284496736f), t, 0.254829592f);
    float e  = __expf(-z * z);
    float er = copysignf(1.0f - p * t * e, z);
    return 0.5f * x * (1.0f + er);
}

// ---------------------------------------------------------------------------
// K0: zero a float buffer
// ---------------------------------------------------------------------------
__global__ void zero_kernel(float* __restrict__ p, int n4) {
    int i = blockIdx.x * 256 + threadIdx.x;
    if (i < n4) ((float4*)p)[i] = make_float4(0.f, 0.f, 0.f, 0.f);
}

// ---------------------------------------------------------------------------
// K1: head-specialized depthwise conv (compile-time k) + channel shuffle.
// ---------------------------------------------------------------------------
template<int HEAD>
__global__ __launch_bounds__(256) void dw_conv(
    const float* __restrict__ x, const float* __restrict__ w,
    const float* __restrict__ bias, u16* __restrict__ dwb)
{
    constexpr int K   = 3 + 2*HEAD;
    constexpr int PAD = HEAD + 1;
    constexpr int R   = 32 + 2*PAD;
    const int tile = blockIdx.x;          // 49
    const int c    = blockIdx.y;          // 16
    const int b    = blockIdx.z;          // 8
    const int th = (tile/7)*32, tw = (tile%7)*32;
    __shared__ float patch[R*40];
    const int tid = threadIdx.x;
    const float* xin = x + (size_t)(b*CIN + HEAD*16 + c)*HWt;
    for (int idx = tid; idx < R*40; idx += 256) {
        int r = idx / 40, cc = idx - r*40;
        int gy = th - PAD + r, gx = tw - 4 + cc;
        float v = 0.f;
        if (gy >= 0 && gy < Hdim && gx >= 0 && gx < Wdim) v = xin[gy*Wdim + gx];
        patch[idx] = v;
    }
    float wreg[K*K];
    const float* wp = w + c*K*K;
    #pragma unroll
    for (int i = 0; i < K*K; i++) wreg[i] = wp[i];
    const float bv = bias[c];
    __syncthreads();

    const int ty = tid >> 3, x0 = (tid & 7) * 4;
    float acc[4] = {bv, bv, bv, bv};
    #pragma unroll
    for (int ky = 0; ky < K; ky++) {
        float rr[12];
        *(float4*)&rr[0] = *(const float4*)&patch[(ty+ky)*40 + x0];
        *(float4*)&rr[4] = *(const float4*)&patch[(ty+ky)*40 + x0 + 4];
        *(float4*)&rr[8] = *(const float4*)&patch[(ty+ky)*40 + x0 + 8];
        #pragma unroll
        for (int kx = 0; kx < K; kx++) {
            const float wv = wreg[ky*K + kx];
            #pragma unroll
            for (int j = 0; j < 4; j++)
                acc[j] = fmaf(rr[j + kx + 4 - PAD], wv, acc[j]);
        }
    }
    const int s = c*4 + HEAD;
    u16 o4[4] = {f2bf(acc[0]), f2bf(acc[1]), f2bf(acc[2]), f2bf(acc[3])};
    *(uint2*)&dwb[(size_t)(b*CIN + s)*HWt + (th+ty)*Wdim + tw + x0] = *(uint2*)o4;
}

// ---------------------------------------------------------------------------
// K2: csc 1x1 via MFMA -> y4 space-to-depth parity layout
// ---------------------------------------------------------------------------
__global__ __launch_bounds__(256) void csc_mfma(
    const float* __restrict__ W, const float* __restrict__ bias,
    const u16* __restrict__ dwb, u16* __restrict__ y4)
{
    const int b  = blockIdx.z;
    const int p0 = blockIdx.x * 128;
    __shared__ u16 Abuf[128*72];
    __shared__ u16 Tbuf[32*132];
    const int tid = threadIdx.x;
    const int wv = tid >> 6, ln = tid & 63;
    const int mh = (wv >> 1)*64, nh = (wv & 1)*64;
    const int lm = ln & 15, kq = ln >> 4;
    for (int t = tid; t < 1024; t += 256) {
        int r = t >> 3, kk = (t & 7)*8;
        const float* src = &W[r*64 + kk];
        float4 f0 = *(const float4*)src, f1 = *(const float4*)(src+4);
        u16 tmp[8] = {f2bf(f0.x),f2bf(f0.y),f2bf(f0.z),f2bf(f0.w),
                      f2bf(f1.x),f2bf(f1.y),f2bf(f1.z),f2bf(f1.w)};
        *(uint4*)&Abuf[r*72 + kk] = *(uint4*)tmp;
    }
    const u16* Db = dwb + (size_t)b*CIN*HWt;
    f32x4 acc[4][4];
    #pragma unroll
    for (int i=0;i<4;i++)
        #pragma unroll
        for (int j=0;j<4;j++) acc[i][j] = (f32x4){0.f,0.f,0.f,0.f};

    for (int kc = 0; kc < 64; kc += 32) {
        __syncthreads();
        for (int t = tid; t < 512; t += 256) {
            int k = t >> 4, n0 = (t & 15)*8;
            *(uint4*)&Tbuf[k*132 + n0] = *(const uint4*)&Db[(size_t)(kc+k)*HWt + p0 + n0];
        }
        __syncthreads();
        bf16x8 af[4], bfr[4];
        #pragma unroll
        for (int tm=0;tm<4;tm++)
            af[tm] = *(bf16x8*)&Abuf[(mh + tm*16 + lm)*72 + kc + kq*8];
        #pragma unroll
        for (int tn=0;tn<4;tn++) {
            int n = nh + tn*16 + lm;
            #pragma unroll
            for (int j=0;j<8;j++) bfr[tn][j] = (short)Tbuf[(kq*8+j)*132 + n];
        }
        #pragma unroll
        for (int tm=0;tm<4;tm++)
            #pragma unroll
            for (int tn=0;tn<4;tn++)
                acc[tm][tn] = MFMA16(af[tm], bfr[tn], acc[tm][tn]);
    }
    #pragma unroll
    for (int tm=0;tm<4;tm++) {
        #pragma unroll
        for (int r=0;r<4;r++) {
            int o = mh + tm*16 + kq*4 + r;
            float bb = bias[o];
            #pragma unroll
            for (int tn=0;tn<4;tn++) {
                int p = p0 + nh + tn*16 + lm;
                int gy = p / 224, gx = p - gy*224;
                int w = (gy&1)*2 + (gx&1);
                y4[((size_t)(b*CO + o)*4 + w)*Lt + (gy>>1)*WO + (gx>>1)]
                    = f2bf(acc[tm][tn][r] + bb);
            }
        }
    }
}

// ---------------------------------------------------------------------------
// K3: BN(eval) -> exact GELU -> dw conv k=7 s=2  (y4 -> gbf)
// v2: conflict-free LDS. Staging writes are LINEAR (one 16B block per lane,
// consecutive lanes -> consecutive blocks). Conv threads own 4 rows x 2 cols
// so consecutive lanes read consecutive 16B blocks (each b128 octet covers
// 8 distinct blocks = all 32 banks). 13 input rows x 3 b128 per thread.
// Tile: 16 out-rows x 112 out-cols, grid (7,128,8). LDS 37*240*4 = 35.5 KB.
// ---------------------------------------------------------------------------
__global__ __launch_bounds__(256) void ggm_kernel(const u16* __restrict__ y4,
    const float* __restrict__ gamma, const float* __restrict__ beta,
    const float* __restrict__ mean, const float* __restrict__ var,
    const float* __restrict__ gw, const float* __restrict__ gb,
    u16* __restrict__ gbf)
{
    const int ho0 = blockIdx.x * 16;      // 7 tiles, exact
    const int c   = blockIdx.y;           // 128
    const int b   = blockIdx.z;           // 8
    // patch rows r=0..36 <-> gy = 2*ho0-3+r ; row = 60 blocks (240 floats),
    // block j covers gx = 4j-8 .. 4j-5 (j 0,1,58,59 are zero pads).
    __shared__ float patch[37*240];
    const int tid = threadIdx.x;

    const float inv = gamma[c] * rsqrtf(var[c] + 1e-5f);
    const float bsh = fmaf(-mean[c], inv, beta[c]);
    const u16* ybc = y4 + (size_t)(b*CO + c)*4*Lt;

    float wk[49];
    const float* wp = gw + c*49;
    #pragma unroll
    for (int i = 0; i < 49; i++) wk[i] = wp[i];
    const float bv = gb[c];

    // ---- stage: linear LDS, one 16B block per lane-iter (conflict-free) ----
    for (int idx = tid; idx < 37*60; idx += 256) {
        int r = idx / 60, j = idx - r*60;
        int gy = 2*ho0 - 3 + r;
        float4 v = make_float4(0.f, 0.f, 0.f, 0.f);
        if (gy >= 0 && gy < Hdim && j >= 2 && j <= 57) {
            // block floats = gx {4j-8,4j-7,4j-6,4j-5} = planes (even,odd) cols 2j-4,2j-3
            const u16* pe = ybc + (size_t)((gy&1)*2)*Lt + (gy>>1)*WO + (2*j - 4);
            unsigned e = *(const unsigned*)pe;        // even-gx pair
            unsigned o = *(const unsigned*)(pe + Lt); // odd-gx pair
            v.x = gelu_fast(fmaf(uasf(e << 16),         inv, bsh));
            v.y = gelu_fast(fmaf(uasf(o << 16),         inv, bsh));
            v.z = gelu_fast(fmaf(uasf(e & 0xffff0000u), inv, bsh));
            v.w = gelu_fast(fmaf(uasf(o & 0xffff0000u), inv, bsh));
        }
        *(float4*)&patch[idx*4] = v;
    }
    __syncthreads();

    // ---- conv: thread -> 4 out-rows x 2 out-cols ----
    if (tid < 224) {
        const int n = tid % 56;           // col pair: wo = 2n, 2n+1
        const int g = tid / 56;           // row group: ho = ho0 + 4g + i
        float acc[4][2];
        #pragma unroll
        for (int i = 0; i < 4; i++) { acc[i][0] = bv; acc[i][1] = bv; }
        #pragma unroll
        for (int rr = 0; rr < 13; rr++) {
            // input patch row r = 8g + rr ; read blocks n+1..n+3
            const float* row = &patch[(8*g + rr)*240 + 4*n + 4];
            float f[12];
            *(float4*)&f[0] = *(const float4*)&row[0];
            *(float4*)&f[4] = *(const float4*)&row[4];
            *(float4*)&f[8] = *(const float4*)&row[8];
            #pragma unroll
            for (int i = 0; i < 4; i++) {
                const int ky = rr - 2*i;
                if (ky >= 0 && ky <= 6) {
                    #pragma unroll
                    for (int kx = 0; kx < 7; kx++) {
                        const float wv = wk[ky*7 + kx];
                        acc[i][0] = fmaf(f[kx + 1], wv, acc[i][0]);
                        acc[i][1] = fmaf(f[kx + 3], wv, acc[i][1]);
                    }
                }
            }
        }
        u16* gout = gbf + (size_t)(b*CO + c)*Lt;
        #pragma unroll
        for (int i = 0; i < 4; i++) {
            u16 o2[2] = {f2bf(acc[i][0]), f2bf(acc[i][1])};
            *(unsigned*)&gout[(ho0 + 4*g + i)*WO + 2*n] = *(unsigned*)o2;
        }
    }
}

// ---------------------------------------------------------------------------
// K4: G_p[b,c2,c'] = sum_l g[c2,l]*tok_p[c',l] via MFMA, split-K atomics.
// ---------------------------------------------------------------------------
__global__ __launch_bounds__(256) void G_mfma(
    const u16* __restrict__ gbf, const u16* __restrict__ y4,
    float* __restrict__ G)
{
    const int b = blockIdx.z, p = blockIdx.y, split = blockIdx.x;  // (32,5,8)
    const u16* Ab = gbf + (size_t)b*CO*Lt;
    const u16* Bb; int brs;
    if (p == 0) { Bb = Ab; brs = Lt; }
    else        { Bb = y4 + ((size_t)b*CO*4 + (p-1))*Lt; brs = 4*Lt; }
    __shared__ u16 Abuf[128*40];
    __shared__ u16 Bbuf[128*40];
    const int tid = threadIdx.x;
    const int wv = tid >> 6, ln = tid & 63;
    const int mh = (wv >> 1)*64, nh = (wv & 1)*64;
    const int lm = ln & 15, kq = ln >> 4;
    f32x4 acc[4][4];
    #pragma unroll
    for (int i=0;i<4;i++)
        #pragma unroll
        for (int j=0;j<4;j++) acc[i][j] = (f32x4){0.f,0.f,0.f,0.f};

    for (int ci = split; ci < 392; ci += 32) {
        const int l0 = ci*32;
        __syncthreads();
        for (int t = tid; t < 512; t += 256) {
            int r = t >> 2, kk = (t & 3)*8;
            *(uint4*)&Abuf[r*40 + kk] = *(const uint4*)&Ab[(size_t)r*Lt  + l0 + kk];
            *(uint4*)&Bbuf[r*40 + kk] = *(const uint4*)&Bb[(size_t)r*brs + l0 + kk];
        }
        __syncthreads();
        bf16x8 af[4], bfr[4];
        #pragma unroll
        for (int tm=0;tm<4;tm++)
            af[tm]  = *(bf16x8*)&Abuf[(mh + tm*16 + lm)*40 + kq*8];
        #pragma unroll
        for (int tn=0;tn<4;tn++)
            bfr[tn] = *(bf16x8*)&Bbuf[(nh + tn*16 + lm)*40 + kq*8];
        #pragma unroll
        for (int tm=0;tm<4;tm++)
            #pragma unroll
            for (int tn=0;tn<4;tn++)
                acc[tm][tn] = MFMA16(af[tm], bfr[tn], acc[tm][tn]);
    }
    float* Go = G + ((size_t)(b*5 + p))*CO*CO;
    #pragma unroll
    for (int tm=0;tm<4;tm++)
        #pragma unroll
        for (int r=0;r<4;r++) {
            int mrow = mh + tm*16 + kq*4 + r;
            #pragma unroll
            for (int tn=0;tn<4;tn++)
                atomicAdd(&Go[mrow*CO + nh + tn*16 + lm], acc[tm][tn][r]);
        }
}

// ---------------------------------------------------------------------------
// K5: S_p[b,c'] column sums (p=0: g; p=1..4: y4 parity rows)
// ---------------------------------------------------------------------------
__global__ void S_kernel(const u16* __restrict__ gbf, const u16* __restrict__ y4,
                         float* __restrict__ S)
{
    const int b = blockIdx.x >> 7, c = blockIdx.x & 127;
    const u16* gr = gbf + (size_t)(b*CO+c)*Lt;
    const u16* yr = y4  + (size_t)(b*CO+c)*4*Lt;
    float vals[5] = {0.f,0.f,0.f,0.f,0.f};
    for (int i = threadIdx.x*8; i < Lt; i += 256*8)
        vals[0] += sum8bf(*(const uint4*)&gr[i]);
    #pragma unroll
    for (int w=0; w<4; w++)
        for (int i = threadIdx.x*8; i < Lt; i += 256*8)
            vals[1+w] += sum8bf(*(const uint4*)&yr[(size_t)w*Lt + i]);
    #pragma unroll
    for (int off=32; off>0; off>>=1) {
        #pragma unroll
        for (int q=0;q<5;q++) vals[q] += __shfl_down(vals[q], off);
    }
    __shared__ float red[4][5];
    const int wid = threadIdx.x>>6, lane = threadIdx.x&63;
    if (lane==0) {
        #pragma unroll
        for (int q=0;q<5;q++) red[wid][q] = vals[q];
    }
    __syncthreads();
    if (threadIdx.x==0) {
        #pragma unroll
        for (int q=0;q<5;q++)
            S[((size_t)b*5 + q)*CO + c] = red[0][q]+red[1][q]+red[2][q]+red[3][q];
    }
}

// ---------------------------------------------------------------------------
// K6: fused KG+logits per (b,p).  KG_p = G_p · kw^T computed as a register-
// tiled fp32 GEMM (KG never leaves LDS), then lanes 0..127 finish
// lg[b,p,c] = qb*ks_p + kb*sq + sum_c2 Qw[c,c2]*KG[c2,c].
// ---------------------------------------------------------------------------
__global__ __launch_bounds__(256) void fused_logits_kernel(
    const float* __restrict__ G, const float* __restrict__ S,
    const float* __restrict__ qkv_w, const float* __restrict__ qkv_b,
    float* __restrict__ lg)
{
    const int p = blockIdx.x, b = blockIdx.y;   // grid (5,8)
    __shared__ float Wl[32*132];                // G chunk, transposed [kk][c2]
    __shared__ float Al[32*132];                // kw^T chunk [kk][c]
    __shared__ float KGl[128*128];              // KG[c2][c]
    const int tid = threadIdx.x;
    const int og = (tid >> 4) * 8;              // c2 tile
    const int pg = (tid & 15) * 8;              // c tile
    const float* Gp = G + (size_t)(b*5 + p)*CO*CO;
    float acc[8][8];
    #pragma unroll
    for (int i=0;i<8;i++)
        #pragma unroll
        for (int j=0;j<8;j++) acc[i][j]=0.f;

    for (int kc = 0; kc < 128; kc += 32) {
        __syncthreads();
        for (int t = tid; t < 4096; t += 256) {
            int kk = t & 31, o = t >> 5;
            Wl[kk*132 + o] = Gp[(size_t)o*CO + kc + kk];          // G[c2][cp]
            Al[kk*132 + o] = qkv_w[(size_t)(CO + o)*CO + kc + kk]; // kw[c][cp]
        }
        __syncthreads();
        #pragma unroll 4
        for (int kk = 0; kk < 32; kk++) {
            float wv[8], av[8];
            *(float4*)&wv[0] = *(const float4*)&Wl[kk*132+og];
            *(float4*)&wv[4] = *(const float4*)&Wl[kk*132+og+4];
            *(float4*)&av[0] = *(const float4*)&Al[kk*132+pg];
            *(float4*)&av[4] = *(const float4*)&Al[kk*132+pg+4];
            #pragma unroll
            for (int i=0;i<8;i++)
                #pragma unroll
                for (int j=0;j<8;j++)
                    acc[i][j] = fmaf(wv[i], av[j], acc[i][j]);
        }
    }
    // KG tile -> LDS
    #pragma unroll
    for (int i=0;i<8;i++) {
        #pragma unroll
        for (int j=0;j<8;j+=4)
            *(float4*)&KGl[(og+i)*128 + pg + j] = *(float4*)&acc[i][j];
    }
    __syncthreads();
    if (tid < 128) {
        const int c = tid;
        const float qb = qkv_b[c], kb = qkv_b[CO + c];
        const float* S0 = S + (size_t)b*5*CO;        // g-token sums
        const float* Sp = S0 + p*CO;                 // token-p sums
        const float* qwrow = qkv_w + (size_t)c*CO;
        const float* kwrow = qkv_w + (size_t)(CO + c)*CO;
        float sq = qb * 12544.f, ks = 0.f, s = 0.f;
        for (int c2 = 0; c2 < CO; c2++) {
            sq = fmaf(qwrow[c2], S0[c2], sq);
            ks = fmaf(kwrow[c2], Sp[c2], ks);
            s  = fmaf(qwrow[c2], KGl[c2*128 + c], s);
        }
        lg[(size_t)(b*5 + p)*CO + c] = s + qb*ks + kb*sq;
    }
}

// ---------------------------------------------------------------------------
// K7: 5-way softmax over p -> a[b,c,p]
// ---------------------------------------------------------------------------
__global__ void softmax5_kernel(const float* __restrict__ lg, float* __restrict__ a)
{
    const int b = blockIdx.x, c = threadIdx.x;  // grid 8 x 128
    float v[5];
    #pragma unroll
    for (int p=0;p<5;p++) v[p] = lg[(size_t)(b*5 + p)*CO + c];
    const float scl = 0.08838834764831845f; // 1/sqrt(128)
    float mx = v[0];
    #pragma unroll
    for (int p=1;p<5;p++) mx = fmaxf(mx, v[p]);
    float e[5], sum = 0.f;
    #pragma unroll
    for (int p=0;p<5;p++){ e[p] = __expf((v[p]-mx)*scl); sum += e[p]; }
    const float rs = 1.f/sum;
    #pragma unroll
    for (int p=0;p<5;p++) a[((size_t)b*CO + c)*5 + p] = e[p]*rs;
}

// ---------------------------------------------------------------------------
// K8: F_p[b,o,c'] = sum_c proj_w[o,c]*a[b,c,p]*Vw[c,c']   (fp32)
// ---------------------------------------------------------------------------
__global__ void F_kernel(const float* __restrict__ proj_w,
    const float* __restrict__ qkv_w, const float* __restrict__ a,
    float* __restrict__ F)
{
    const int b = blockIdx.z, p = blockIdx.y;   // (64,5,8) x 256
    const int o  = blockIdx.x*2 + (threadIdx.x>>7);
    const int cp = threadIdx.x & 127;
    const float* vw = qkv_w + 2*CO*CO;
    float s = 0.f;
    for (int c=0;c<CO;c++)
        s = fmaf(proj_w[o*CO+c] * a[((size_t)b*CO+c)*5 + p], vw[c*CO+cp], s);
    F[(((size_t)(b*5+p))*CO + o)*CO + cp] = s;
}

// ---------------------------------------------------------------------------
// K9: biasout[o] = proj_b[o] + sum_c proj_w[o,c]*vb[c]
// ---------------------------------------------------------------------------
__global__ void bias_kernel(const float* __restrict__ proj_w,
    const float* __restrict__ proj_b, const float* __restrict__ qkv_b,
    float* __restrict__ biasout)
{
    const int o = threadIdx.x; // 128
    const float* vb = qkv_b + 2*CO;
    float s = proj_b[o];
    for (int c=0;c<CO;c++) s = fmaf(proj_w[o*CO+c], vb[c], s);
    biasout[o] = s;
}

// ---------------------------------------------------------------------------
// K10: out[b,o,l] = sum_p F_p[o,:]·tok_p[:,l] + biasout[o]  via MFMA
// ---------------------------------------------------------------------------
__global__ __launch_bounds__(256) void final_mfma(
    const float* __restrict__ F, const u16* __restrict__ gbf,
    const u16* __restrict__ y4, const float* __restrict__ biasout,
    float* __restrict__ out)
{
    const int b = blockIdx.z;
    const int p0 = blockIdx.x * 128;
    __shared__ u16 Abuf[128*40];
    __shared__ u16 Tbuf[32*132];
    const int tid = threadIdx.x;
    const int wv = tid >> 6, ln = tid & 63;
    const int mh = (wv >> 1)*64, nh = (wv & 1)*64;
    const int lm = ln & 15, kq = ln >> 4;
    f32x4 acc[4][4];
    #pragma unroll
    for (int i=0;i<4;i++)
        #pragma unroll
        for (int j=0;j<4;j++) acc[i][j] = (f32x4){0.f,0.f,0.f,0.f};

    for (int ph = 0; ph < 5; ph++) {
        const float* Fp = F + (size_t)(b*5 + ph)*CO*CO;
        const u16* Bb; int brs;
        if (ph == 0) { Bb = gbf + (size_t)b*CO*Lt; brs = Lt; }
        else         { Bb = y4 + ((size_t)b*CO*4 + (ph-1))*Lt; brs = 4*Lt; }
        for (int kc = 0; kc < CO; kc += 32) {
            __syncthreads();
            for (int t = tid; t < 512; t += 256) {
                int r = t >> 2, kk = (t & 3)*8;
                const float* src = &Fp[r*CO + kc + kk];
                float4 f0 = *(const float4*)src, f1 = *(const float4*)(src+4);
                u16 tmp[8] = {f2bf(f0.x),f2bf(f0.y),f2bf(f0.z),f2bf(f0.w),
                              f2bf(f1.x),f2bf(f1.y),f2bf(f1.z),f2bf(f1.w)};
                *(uint4*)&Abuf[r*40 + kk] = *(uint4*)tmp;
            }
            for (int t = tid; t < 512; t += 256) {
                int k = t >> 4, n0 = (t & 15)*8;
                *(uint4*)&Tbuf[k*132 + n0] = *(const uint4*)&Bb[(size_t)(kc+k)*brs + p0 + n0];
            }
            __syncthreads();
            bf16x8 af[4], bfr[4];
            #pragma unroll
            for (int tm=0;tm<4;tm++)
                af[tm] = *(bf16x8*)&Abuf[(mh + tm*16 + lm)*40 + kq*8];
            #pragma unroll
            for (int tn=0;tn<4;tn++) {
                int n = nh + tn*16 + lm;
                #pragma unroll
                for (int j=0;j<8;j++) bfr[tn][j] = (short)Tbuf[(kq*8+j)*132 + n];
            }
            #pragma unroll
            for (int tm=0;tm<4;tm++)
                #pragma unroll
                for (int tn=0;tn<4;tn++)
                    acc[tm][tn] = MFMA16(af[tm], bfr[tn], acc[tm][tn]);
        }
    }
    float* Ob = out + (size_t)b*CO*Lt;
    #pragma unroll
    for (int tm=0;tm<4;tm++) {
        #pragma unroll
        for (int r=0;r<4;r++) {
            int o = mh + tm*16 + kq*4 + r;
            float bb = biasout[o];
            #pragma unroll
            for (int tn=0;tn<4;tn++)
                Ob[(size_t)o*Lt + p0 + nh + tn*16 + lm] = acc[tm][tn][r] + bb;
        }
    }
}

// ---------------------------------------------------------------------------
extern "C" void kernel_launch(void* const* d_in, const int* in_sizes, int n_in,
                              void* d_out, int out_size, void* d_ws, size_t ws_size,
                              hipStream_t stream) {
    const float* x      = (const float*)d_in[0];
    const float* dw_w0  = (const float*)d_in[1];
    const float* dw_b0  = (const float*)d_in[2];
    const float* dw_w1  = (const float*)d_in[3];
    const float* dw_b1  = (const float*)d_in[4];
    const float* dw_w2  = (const float*)d_in[5];
    const float* dw_b2  = (const float*)d_in[6];
    const float* dw_w3  = (const float*)d_in[7];
    const float* dw_b3  = (const float*)d_in[8];
    const float* csc_w  = (const float*)d_in[9];
    const float* csc_b  = (const float*)d_in[10];
    const float* bn_g   = (const float*)d_in[11];
    const float* bn_b   = (const float*)d_in[12];
    const float* bn_m   = (const float*)d_in[13];
    const float* bn_v   = (const float*)d_in[14];
    const float* ggm_w  = (const float*)d_in[15];
    const float* ggm_b  = (const float*)d_in[16];
    const float* qkv_w  = (const float*)d_in[17];
    const float* qkv_b  = (const float*)d_in[18];
    const float* proj_w = (const float*)d_in[19];
    const float* proj_b = (const float*)d_in[20];
    float* out = (float*)d_out;

    // workspace layout (bytes; all 16B-aligned)
    char* ws = (char*)d_ws;
    u16*   y4  = (u16*)(ws);                          // 102,760,448 B
    u16*   dwb = (u16*)(ws + 102760448);              //  51,380,224 B
    u16*   gbf = (u16*)(ws + 154140672);              //  25,690,112 B
    float* G   = (float*)(ws + 179830784);            // 655,360 f32
    float* lgb = G  + 655360;                         // 5,120
    float* F   = lgb + 5120;                          // 655,360
    float* S   = F  + 655360;                         // 5,120
    float* aw  = S  + 5120;                           // 5,120
    float* bo  = aw + 5120;                           // 128

    zero_kernel<<<dim3(640), 256, 0, stream>>>(G, 655360/4);

    dw_conv<0><<<dim3(49, 16, 8), 256, 0, stream>>>(x, dw_w0, dw_b0, dwb);
    dw_conv<1><<<dim3(49, 16, 8), 256, 0, stream>>>(x, dw_w1, dw_b1, dwb);
    dw_conv<2><<<dim3(49, 16, 8), 256, 0, stream>>>(x, dw_w2, dw_b2, dwb);
    dw_conv<3><<<dim3(49, 16, 8), 256, 0, stream>>>(x, dw_w3, dw_b3, dwb);

    csc_mfma<<<dim3(392, 1, 8), 256, 0, stream>>>(csc_w, csc_b, dwb, y4);

    ggm_kernel<<<dim3(7, 128, 8), 256, 0, stream>>>(
        y4, bn_g, bn_b, bn_m, bn_v, ggm_w, ggm_b, gbf);

    G_mfma<<<dim3(32, 5, 8), 256, 0, stream>>>(gbf, y4, G);

    S_kernel<<<dim3(1024), 256, 0, stream>>>(gbf, y4, S);

    fused_logits_kernel<<<dim3(5, 8), 256, 0, stream>>>(G, S, qkv_w, qkv_b, lgb);

    softmax5_kernel<<<dim3(8), 128, 0, stream>>>(lgb, aw);

    F_kernel<<<dim3(64, 5, 8), 256, 0, stream>>>(proj_w, qkv_w, aw, F);
    bias_kernel<<<dim3(1), 128, 0, stream>>>(proj_w, proj_b, qkv_b, bo);

    final_mfma<<<dim3(98, 1, 8), 256, 0, stream>>>(F, gbf, y4, bo, out);
}

// Round 3
// 626.406 us; speedup vs baseline: 1.1649x; 1.1076x over previous
//
#include <hip/hip_runtime.h>

#define BB 8
#define CIN 64
#define CO 128
#define Hdim 224
#define Wdim 224
#define HWt (224*224)
#define HO 112
#define WO 112
#define Lt (112*112)

typedef unsigned short u16;
typedef short bf16x8 __attribute__((ext_vector_type(8)));
typedef float f32x4  __attribute__((ext_vector_type(4)));
#define MFMA16(a,b,c) __builtin_amdgcn_mfma_f32_16x16x32_bf16((a),(b),(c),0,0,0)

__device__ inline u16 f2bf(float f) {
    union { float f; unsigned u; } v; v.f = f;
    unsigned r = (v.u + 0x7fffu + ((v.u >> 16) & 1u)) >> 16;
    return (u16)r;
}
__device__ inline float bf2f(u16 h) {
    union { unsigned u; float f; } v; v.u = ((unsigned)h) << 16; return v.f;
}
__device__ inline float uasf(unsigned u) {
    union { unsigned u; float f; } v; v.u = u; return v.f;
}
__device__ inline float sum8bf(uint4 v) {
    return bf2f(v.x & 0xffff) + bf2f(v.x >> 16) + bf2f(v.y & 0xffff) + bf2f(v.y >> 16)
         + bf2f(v.z & 0xffff) + bf2f(v.z >> 16) + bf2f(v.w & 0xffff) + bf2f(v.w >> 16);
}

// exact-GELU via Abramowitz-Stegun 7.1.26 erf (max |err| 1.5e-7), ~18 VALU ops
__device__ inline float gelu_fast(float x) {
    float z  = x * 0.7071067811865476f;
    float az = fabsf(z);
    float t  = __builtin_amdgcn_rcpf(fmaf(0.3275911f, az, 1.0f));
    float p  = fmaf(fmaf(fmaf(fmaf(1.061405429f, t, -1.453152027f), t,
                    1.421413741f), t, -0.284496736f), t, 0.254829592f);
    float e  = __expf(-z * z);
    float er = copysignf(1.0f - p * t * e, z);
    return 0.5f * x * (1.0f + er);
}

// ---------------------------------------------------------------------------
// K1: head-specialized depthwise conv (compile-time k) + channel shuffle.
// ---------------------------------------------------------------------------
template<int HEAD>
__global__ __launch_bounds__(256) void dw_conv(
    const float* __restrict__ x, const float* __restrict__ w,
    const float* __restrict__ bias, u16* __restrict__ dwb)
{
    constexpr int K   = 3 + 2*HEAD;
    constexpr int PAD = HEAD + 1;
    constexpr int R   = 32 + 2*PAD;
    const int tile = blockIdx.x;          // 49
    const int c    = blockIdx.y;          // 16
    const int b    = blockIdx.z;          // 8
    const int th = (tile/7)*32, tw = (tile%7)*32;
    __shared__ float patch[R*40];
    const int tid = threadIdx.x;
    const float* xin = x + (size_t)(b*CIN + HEAD*16 + c)*HWt;
    for (int idx = tid; idx < R*40; idx += 256) {
        int r = idx / 40, cc = idx - r*40;
        int gy = th - PAD + r, gx = tw - 4 + cc;
        float v = 0.f;
        if (gy >= 0 && gy < Hdim && gx >= 0 && gx < Wdim) v = xin[gy*Wdim + gx];
        patch[idx] = v;
    }
    float wreg[K*K];
    const float* wp = w + c*K*K;
    #pragma unroll
    for (int i = 0; i < K*K; i++) wreg[i] = wp[i];
    const float bv = bias[c];
    __syncthreads();

    const int ty = tid >> 3, x0 = (tid & 7) * 4;
    float acc[4] = {bv, bv, bv, bv};
    #pragma unroll
    for (int ky = 0; ky < K; ky++) {
        float rr[12];
        *(float4*)&rr[0] = *(const float4*)&patch[(ty+ky)*40 + x0];
        *(float4*)&rr[4] = *(const float4*)&patch[(ty+ky)*40 + x0 + 4];
        *(float4*)&rr[8] = *(const float4*)&patch[(ty+ky)*40 + x0 + 8];
        #pragma unroll
        for (int kx = 0; kx < K; kx++) {
            const float wv = wreg[ky*K + kx];
            #pragma unroll
            for (int j = 0; j < 4; j++)
                acc[j] = fmaf(rr[j + kx + 4 - PAD], wv, acc[j]);
        }
    }
    const int s = c*4 + HEAD;
    u16 o4[4] = {f2bf(acc[0]), f2bf(acc[1]), f2bf(acc[2]), f2bf(acc[3])};
    *(uint2*)&dwb[(size_t)(b*CIN + s)*HWt + (th+ty)*Wdim + tw + x0] = *(uint2*)o4;
}

// ---------------------------------------------------------------------------
// K2: csc 1x1 via MFMA -> y4 space-to-depth parity layout
// ---------------------------------------------------------------------------
__global__ __launch_bounds__(256) void csc_mfma(
    const float* __restrict__ W, const float* __restrict__ bias,
    const u16* __restrict__ dwb, u16* __restrict__ y4)
{
    const int b  = blockIdx.z;
    const int p0 = blockIdx.x * 128;
    __shared__ u16 Abuf[128*72];
    __shared__ u16 Tbuf[32*132];
    const int tid = threadIdx.x;
    const int wv = tid >> 6, ln = tid & 63;
    const int mh = (wv >> 1)*64, nh = (wv & 1)*64;
    const int lm = ln & 15, kq = ln >> 4;
    for (int t = tid; t < 1024; t += 256) {
        int r = t >> 3, kk = (t & 7)*8;
        const float* src = &W[r*64 + kk];
        float4 f0 = *(const float4*)src, f1 = *(const float4*)(src+4);
        u16 tmp[8] = {f2bf(f0.x),f2bf(f0.y),f2bf(f0.z),f2bf(f0.w),
                      f2bf(f1.x),f2bf(f1.y),f2bf(f1.z),f2bf(f1.w)};
        *(uint4*)&Abuf[r*72 + kk] = *(uint4*)tmp;
    }
    const u16* Db = dwb + (size_t)b*CIN*HWt;
    f32x4 acc[4][4];
    #pragma unroll
    for (int i=0;i<4;i++)
        #pragma unroll
        for (int j=0;j<4;j++) acc[i][j] = (f32x4){0.f,0.f,0.f,0.f};

    for (int kc = 0; kc < 64; kc += 32) {
        __syncthreads();
        for (int t = tid; t < 512; t += 256) {
            int k = t >> 4, n0 = (t & 15)*8;
            *(uint4*)&Tbuf[k*132 + n0] = *(const uint4*)&Db[(size_t)(kc+k)*HWt + p0 + n0];
        }
        __syncthreads();
        bf16x8 af[4], bfr[4];
        #pragma unroll
        for (int tm=0;tm<4;tm++)
            af[tm] = *(bf16x8*)&Abuf[(mh + tm*16 + lm)*72 + kc + kq*8];
        #pragma unroll
        for (int tn=0;tn<4;tn++) {
            int n = nh + tn*16 + lm;
            #pragma unroll
            for (int j=0;j<8;j++) bfr[tn][j] = (short)Tbuf[(kq*8+j)*132 + n];
        }
        #pragma unroll
        for (int tm=0;tm<4;tm++)
            #pragma unroll
            for (int tn=0;tn<4;tn++)
                acc[tm][tn] = MFMA16(af[tm], bfr[tn], acc[tm][tn]);
    }
    #pragma unroll
    for (int tm=0;tm<4;tm++) {
        #pragma unroll
        for (int r=0;r<4;r++) {
            int o = mh + tm*16 + kq*4 + r;
            float bb = bias[o];
            #pragma unroll
            for (int tn=0;tn<4;tn++) {
                int p = p0 + nh + tn*16 + lm;
                int gy = p / 224, gx = p - gy*224;
                int w = (gy&1)*2 + (gx&1);
                y4[((size_t)(b*CO + o)*4 + w)*Lt + (gy>>1)*WO + (gx>>1)]
                    = f2bf(acc[tm][tn][r] + bb);
            }
        }
    }
}

// ---------------------------------------------------------------------------
// K3: BN(eval) -> exact GELU -> dw conv k=7 s=2  (y4 -> gbf)
// Conflict-free LDS; linear staging writes; conv threads own 4 rows x 2 cols.
// ---------------------------------------------------------------------------
__global__ __launch_bounds__(256) void ggm_kernel(const u16* __restrict__ y4,
    const float* __restrict__ gamma, const float* __restrict__ beta,
    const float* __restrict__ mean, const float* __restrict__ var,
    const float* __restrict__ gw, const float* __restrict__ gb,
    u16* __restrict__ gbf)
{
    const int ho0 = blockIdx.x * 16;      // 7 tiles, exact
    const int c   = blockIdx.y;           // 128
    const int b   = blockIdx.z;           // 8
    __shared__ float patch[37*240];
    const int tid = threadIdx.x;

    const float inv = gamma[c] * rsqrtf(var[c] + 1e-5f);
    const float bsh = fmaf(-mean[c], inv, beta[c]);
    const u16* ybc = y4 + (size_t)(b*CO + c)*4*Lt;

    float wk[49];
    const float* wp = gw + c*49;
    #pragma unroll
    for (int i = 0; i < 49; i++) wk[i] = wp[i];
    const float bv = gb[c];

    for (int idx = tid; idx < 37*60; idx += 256) {
        int r = idx / 60, j = idx - r*60;
        int gy = 2*ho0 - 3 + r;
        float4 v = make_float4(0.f, 0.f, 0.f, 0.f);
        if (gy >= 0 && gy < Hdim && j >= 2 && j <= 57) {
            const u16* pe = ybc + (size_t)((gy&1)*2)*Lt + (gy>>1)*WO + (2*j - 4);
            unsigned e = *(const unsigned*)pe;        // even-gx pair
            unsigned o = *(const unsigned*)(pe + Lt); // odd-gx pair
            v.x = gelu_fast(fmaf(uasf(e << 16),         inv, bsh));
            v.y = gelu_fast(fmaf(uasf(o << 16),         inv, bsh));
            v.z = gelu_fast(fmaf(uasf(e & 0xffff0000u), inv, bsh));
            v.w = gelu_fast(fmaf(uasf(o & 0xffff0000u), inv, bsh));
        }
        *(float4*)&patch[idx*4] = v;
    }
    __syncthreads();

    if (tid < 224) {
        const int n = tid % 56;           // col pair: wo = 2n, 2n+1
        const int g = tid / 56;           // row group: ho = ho0 + 4g + i
        float acc[4][2];
        #pragma unroll
        for (int i = 0; i < 4; i++) { acc[i][0] = bv; acc[i][1] = bv; }
        #pragma unroll
        for (int rr = 0; rr < 13; rr++) {
            const float* row = &patch[(8*g + rr)*240 + 4*n + 4];
            float f[12];
            *(float4*)&f[0] = *(const float4*)&row[0];
            *(float4*)&f[4] = *(const float4*)&row[4];
            *(float4*)&f[8] = *(const float4*)&row[8];
            #pragma unroll
            for (int i = 0; i < 4; i++) {
                const int ky = rr - 2*i;
                if (ky >= 0 && ky <= 6) {
                    #pragma unroll
                    for (int kx = 0; kx < 7; kx++) {
                        const float wv = wk[ky*7 + kx];
                        acc[i][0] = fmaf(f[kx + 1], wv, acc[i][0]);
                        acc[i][1] = fmaf(f[kx + 3], wv, acc[i][1]);
                    }
                }
            }
        }
        u16* gout = gbf + (size_t)(b*CO + c)*Lt;
        #pragma unroll
        for (int i = 0; i < 4; i++) {
            u16 o2[2] = {f2bf(acc[i][0]), f2bf(acc[i][1])};
            *(unsigned*)&gout[(ho0 + 4*g + i)*WO + 2*n] = *(unsigned*)o2;
        }
    }
}

// ---------------------------------------------------------------------------
// K4: G partials via MFMA, BK=64, split-K=16, NO atomics (plain stores).
// Gpart[(split*40 + b*5 + p)][c2][c']
// ---------------------------------------------------------------------------
__global__ __launch_bounds__(256) void G_mfma(
    const u16* __restrict__ gbf, const u16* __restrict__ y4,
    float* __restrict__ Gpart)
{
    const int b = blockIdx.z, p = blockIdx.y, split = blockIdx.x;  // (16,5,8)
    const u16* Ab = gbf + (size_t)b*CO*Lt;
    const u16* Bb; int brs;
    if (p == 0) { Bb = Ab; brs = Lt; }
    else        { Bb = y4 + ((size_t)b*CO*4 + (p-1))*Lt; brs = 4*Lt; }
    __shared__ u16 Abuf[128*72];
    __shared__ u16 Bbuf[128*72];
    const int tid = threadIdx.x;
    const int wv = tid >> 6, ln = tid & 63;
    const int mh = (wv >> 1)*64, nh = (wv & 1)*64;
    const int lm = ln & 15, kq = ln >> 4;
    f32x4 acc[4][4];
    #pragma unroll
    for (int i=0;i<4;i++)
        #pragma unroll
        for (int j=0;j<4;j++) acc[i][j] = (f32x4){0.f,0.f,0.f,0.f};

    for (int ci = split; ci < 196; ci += 16) {   // 196 chunks of BK=64
        const int l0 = ci*64;
        __syncthreads();
        for (int t = tid; t < 1024; t += 256) {
            int r = t >> 3, kk = (t & 7)*8;
            *(uint4*)&Abuf[r*72 + kk] = *(const uint4*)&Ab[(size_t)r*Lt  + l0 + kk];
            *(uint4*)&Bbuf[r*72 + kk] = *(const uint4*)&Bb[(size_t)r*brs + l0 + kk];
        }
        __syncthreads();
        #pragma unroll
        for (int ks = 0; ks < 2; ks++) {
            bf16x8 af[4], bfr[4];
            #pragma unroll
            for (int tm=0;tm<4;tm++)
                af[tm]  = *(bf16x8*)&Abuf[(mh + tm*16 + lm)*72 + ks*32 + kq*8];
            #pragma unroll
            for (int tn=0;tn<4;tn++)
                bfr[tn] = *(bf16x8*)&Bbuf[(nh + tn*16 + lm)*72 + ks*32 + kq*8];
            #pragma unroll
            for (int tm=0;tm<4;tm++)
                #pragma unroll
                for (int tn=0;tn<4;tn++)
                    acc[tm][tn] = MFMA16(af[tm], bfr[tn], acc[tm][tn]);
        }
    }
    float* Go = Gpart + ((size_t)(split*40) + b*5 + p)*CO*CO;
    #pragma unroll
    for (int tm=0;tm<4;tm++)
        #pragma unroll
        for (int r=0;r<4;r++) {
            int mrow = mh + tm*16 + kq*4 + r;
            #pragma unroll
            for (int tn=0;tn<4;tn++)
                Go[mrow*CO + nh + tn*16 + lm] = acc[tm][tn][r];
        }
}

// ---------------------------------------------------------------------------
// K4b: G[bp] = sum over 16 splits of Gpart  (grid (40,16) x 256, float4/thr)
// ---------------------------------------------------------------------------
__global__ void G_reduce(const float* __restrict__ Gpart, float* __restrict__ G)
{
    const int bp = blockIdx.x;
    const int i4 = (blockIdx.y*256 + threadIdx.x)*4;   // < 16384
    float4 s = make_float4(0.f, 0.f, 0.f, 0.f);
    #pragma unroll
    for (int sp = 0; sp < 16; sp++) {
        float4 v = *(const float4*)&Gpart[((size_t)(sp*40) + bp)*CO*CO + i4];
        s.x += v.x; s.y += v.y; s.z += v.z; s.w += v.w;
    }
    *(float4*)&G[(size_t)bp*CO*CO + i4] = s;
}

// ---------------------------------------------------------------------------
// K5: S_p[b,c'] column sums (p=0: g; p=1..4: y4 parity rows)
// ---------------------------------------------------------------------------
__global__ void S_kernel(const u16* __restrict__ gbf, const u16* __restrict__ y4,
                         float* __restrict__ S)
{
    const int b = blockIdx.x >> 7, c = blockIdx.x & 127;
    const u16* gr = gbf + (size_t)(b*CO+c)*Lt;
    const u16* yr = y4  + (size_t)(b*CO+c)*4*Lt;
    float vals[5] = {0.f,0.f,0.f,0.f,0.f};
    for (int i = threadIdx.x*8; i < Lt; i += 256*8)
        vals[0] += sum8bf(*(const uint4*)&gr[i]);
    #pragma unroll
    for (int w=0; w<4; w++)
        for (int i = threadIdx.x*8; i < Lt; i += 256*8)
            vals[1+w] += sum8bf(*(const uint4*)&yr[(size_t)w*Lt + i]);
    #pragma unroll
    for (int off=32; off>0; off>>=1) {
        #pragma unroll
        for (int q=0;q<5;q++) vals[q] += __shfl_down(vals[q], off);
    }
    __shared__ float red[4][5];
    const int wid = threadIdx.x>>6, lane = threadIdx.x&63;
    if (lane==0) {
        #pragma unroll
        for (int q=0;q<5;q++) red[wid][q] = vals[q];
    }
    __syncthreads();
    if (threadIdx.x==0) {
        #pragma unroll
        for (int q=0;q<5;q++)
            S[((size_t)b*5 + q)*CO + c] = red[0][q]+red[1][q]+red[2][q]+red[3][q];
    }
}

// ---------------------------------------------------------------------------
// K6: fused KG+logits per (b,p).
// ---------------------------------------------------------------------------
__global__ __launch_bounds__(256) void fused_logits_kernel(
    const float* __restrict__ G, const float* __restrict__ S,
    const float* __restrict__ qkv_w, const float* __restrict__ qkv_b,
    float* __restrict__ lg)
{
    const int p = blockIdx.x, b = blockIdx.y;   // grid (5,8)
    __shared__ float Wl[32*132];                // G chunk, transposed [kk][c2]
    __shared__ float Al[32*132];                // kw^T chunk [kk][c]
    __shared__ float KGl[128*128];              // KG[c2][c]
    const int tid = threadIdx.x;
    const int og = (tid >> 4) * 8;              // c2 tile
    const int pg = (tid & 15) * 8;              // c tile
    const float* Gp = G + (size_t)(b*5 + p)*CO*CO;
    float acc[8][8];
    #pragma unroll
    for (int i=0;i<8;i++)
        #pragma unroll
        for (int j=0;j<8;j++) acc[i][j]=0.f;

    for (int kc = 0; kc < 128; kc += 32) {
        __syncthreads();
        for (int t = tid; t < 4096; t += 256) {
            int kk = t & 31, o = t >> 5;
            Wl[kk*132 + o] = Gp[(size_t)o*CO + kc + kk];          // G[c2][cp]
            Al[kk*132 + o] = qkv_w[(size_t)(CO + o)*CO + kc + kk]; // kw[c][cp]
        }
        __syncthreads();
        #pragma unroll 4
        for (int kk = 0; kk < 32; kk++) {
            float wv[8], av[8];
            *(float4*)&wv[0] = *(const float4*)&Wl[kk*132+og];
            *(float4*)&wv[4] = *(const float4*)&Wl[kk*132+og+4];
            *(float4*)&av[0] = *(const float4*)&Al[kk*132+pg];
            *(float4*)&av[4] = *(const float4*)&Al[kk*132+pg+4];
            #pragma unroll
            for (int i=0;i<8;i++)
                #pragma unroll
                for (int j=0;j<8;j++)
                    acc[i][j] = fmaf(wv[i], av[j], acc[i][j]);
        }
    }
    #pragma unroll
    for (int i=0;i<8;i++) {
        #pragma unroll
        for (int j=0;j<8;j+=4)
            *(float4*)&KGl[(og+i)*128 + pg + j] = *(float4*)&acc[i][j];
    }
    __syncthreads();
    if (tid < 128) {
        const int c = tid;
        const float qb = qkv_b[c], kb = qkv_b[CO + c];
        const float* S0 = S + (size_t)b*5*CO;        // g-token sums
        const float* Sp = S0 + p*CO;                 // token-p sums
        const float* qwrow = qkv_w + (size_t)c*CO;
        const float* kwrow = qkv_w + (size_t)(CO + c)*CO;
        float sq = qb * 12544.f, ks = 0.f, s = 0.f;
        for (int c2 = 0; c2 < CO; c2++) {
            sq = fmaf(qwrow[c2], S0[c2], sq);
            ks = fmaf(kwrow[c2], Sp[c2], ks);
            s  = fmaf(qwrow[c2], KGl[c2*128 + c], s);
        }
        lg[(size_t)(b*5 + p)*CO + c] = s + qb*ks + kb*sq;
    }
}

// ---------------------------------------------------------------------------
// K7: 5-way softmax over p -> a[b,c,p]
// ---------------------------------------------------------------------------
__global__ void softmax5_kernel(const float* __restrict__ lg, float* __restrict__ a)
{
    const int b = blockIdx.x, c = threadIdx.x;  // grid 8 x 128
    float v[5];
    #pragma unroll
    for (int p=0;p<5;p++) v[p] = lg[(size_t)(b*5 + p)*CO + c];
    const float scl = 0.08838834764831845f; // 1/sqrt(128)
    float mx = v[0];
    #pragma unroll
    for (int p=1;p<5;p++) mx = fmaxf(mx, v[p]);
    float e[5], sum = 0.f;
    #pragma unroll
    for (int p=0;p<5;p++){ e[p] = __expf((v[p]-mx)*scl); sum += e[p]; }
    const float rs = 1.f/sum;
    #pragma unroll
    for (int p=0;p<5;p++) a[((size_t)b*CO + c)*5 + p] = e[p]*rs;
}

// ---------------------------------------------------------------------------
// K8: F_p[b,o,c'] = sum_c proj_w[o,c]*a[b,c,p]*Vw[c,c']   (fp32)
// ---------------------------------------------------------------------------
__global__ void F_kernel(const float* __restrict__ proj_w,
    const float* __restrict__ qkv_w, const float* __restrict__ a,
    float* __restrict__ F)
{
    const int b = blockIdx.z, p = blockIdx.y;   // (64,5,8) x 256
    const int o  = blockIdx.x*2 + (threadIdx.x>>7);
    const int cp = threadIdx.x & 127;
    const float* vw = qkv_w + 2*CO*CO;
    float s = 0.f;
    for (int c=0;c<CO;c++)
        s = fmaf(proj_w[o*CO+c] * a[((size_t)b*CO+c)*5 + p], vw[c*CO+cp], s);
    F[(((size_t)(b*5+p))*CO + o)*CO + cp] = s;
}

// ---------------------------------------------------------------------------
// K9: biasout[o] = proj_b[o] + sum_c proj_w[o,c]*vb[c]
// ---------------------------------------------------------------------------
__global__ void bias_kernel(const float* __restrict__ proj_w,
    const float* __restrict__ proj_b, const float* __restrict__ qkv_b,
    float* __restrict__ biasout)
{
    const int o = threadIdx.x; // 128
    const float* vb = qkv_b + 2*CO;
    float s = proj_b[o];
    for (int c=0;c<CO;c++) s = fmaf(proj_w[o*CO+c], vb[c], s);
    biasout[o] = s;
}

// ---------------------------------------------------------------------------
// K10: out[b,o,l] = sum_p F_p[o,:]·tok_p[:,l] + biasout[o]  via MFMA
// ---------------------------------------------------------------------------
__global__ __launch_bounds__(256) void final_mfma(
    const float* __restrict__ F, const u16* __restrict__ gbf,
    const u16* __restrict__ y4, const float* __restrict__ biasout,
    float* __restrict__ out)
{
    const int b = blockIdx.z;
    const int p0 = blockIdx.x * 128;
    __shared__ u16 Abuf[128*40];
    __shared__ u16 Tbuf[32*132];
    const int tid = threadIdx.x;
    const int wv = tid >> 6, ln = tid & 63;
    const int mh = (wv >> 1)*64, nh = (wv & 1)*64;
    const int lm = ln & 15, kq = ln >> 4;
    f32x4 acc[4][4];
    #pragma unroll
    for (int i=0;i<4;i++)
        #pragma unroll
        for (int j=0;j<4;j++) acc[i][j] = (f32x4){0.f,0.f,0.f,0.f};

    for (int ph = 0; ph < 5; ph++) {
        const float* Fp = F + (size_t)(b*5 + ph)*CO*CO;
        const u16* Bb; int brs;
        if (ph == 0) { Bb = gbf + (size_t)b*CO*Lt; brs = Lt; }
        else         { Bb = y4 + ((size_t)b*CO*4 + (ph-1))*Lt; brs = 4*Lt; }
        for (int kc = 0; kc < CO; kc += 32) {
            __syncthreads();
            for (int t = tid; t < 512; t += 256) {
                int r = t >> 2, kk = (t & 3)*8;
                const float* src = &Fp[r*CO + kc + kk];
                float4 f0 = *(const float4*)src, f1 = *(const float4*)(src+4);
                u16 tmp[8] = {f2bf(f0.x),f2bf(f0.y),f2bf(f0.z),f2bf(f0.w),
                              f2bf(f1.x),f2bf(f1.y),f2bf(f1.z),f2bf(f1.w)};
                *(uint4*)&Abuf[r*40 + kk] = *(uint4*)tmp;
            }
            for (int t = tid; t < 512; t += 256) {
                int k = t >> 4, n0 = (t & 15)*8;
                *(uint4*)&Tbuf[k*132 + n0] = *(const uint4*)&Bb[(size_t)(kc+k)*brs + p0 + n0];
            }
            __syncthreads();
            bf16x8 af[4], bfr[4];
            #pragma unroll
            for (int tm=0;tm<4;tm++)
                af[tm] = *(bf16x8*)&Abuf[(mh + tm*16 + lm)*40 + kq*8];
            #pragma unroll
            for (int tn=0;tn<4;tn++) {
                int n = nh + tn*16 + lm;
                #pragma unroll
                for (int j=0;j<8;j++) bfr[tn][j] = (short)Tbuf[(kq*8+j)*132 + n];
            }
            #pragma unroll
            for (int tm=0;tm<4;tm++)
                #pragma unroll
                for (int tn=0;tn<4;tn++)
                    acc[tm][tn] = MFMA16(af[tm], bfr[tn], acc[tm][tn]);
        }
    }
    float* Ob = out + (size_t)b*CO*Lt;
    #pragma unroll
    for (int tm=0;tm<4;tm++) {
        #pragma unroll
        for (int r=0;r<4;r++) {
            int o = mh + tm*16 + kq*4 + r;
            float bb = biasout[o];
            #pragma unroll
            for (int tn=0;tn<4;tn++)
                Ob[(size_t)o*Lt + p0 + nh + tn*16 + lm] = acc[tm][tn][r] + bb;
        }
    }
}

// ---------------------------------------------------------------------------
extern "C" void kernel_launch(void* const* d_in, const int* in_sizes, int n_in,
                              void* d_out, int out_size, void* d_ws, size_t ws_size,
                              hipStream_t stream) {
    const float* x      = (const float*)d_in[0];
    const float* dw_w0  = (const float*)d_in[1];
    const float* dw_b0  = (const float*)d_in[2];
    const float* dw_w1  = (const float*)d_in[3];
    const float* dw_b1  = (const float*)d_in[4];
    const float* dw_w2  = (const float*)d_in[5];
    const float* dw_b2  = (const float*)d_in[6];
    const float* dw_w3  = (const float*)d_in[7];
    const float* dw_b3  = (const float*)d_in[8];
    const float* csc_w  = (const float*)d_in[9];
    const float* csc_b  = (const float*)d_in[10];
    const float* bn_g   = (const float*)d_in[11];
    const float* bn_b   = (const float*)d_in[12];
    const float* bn_m   = (const float*)d_in[13];
    const float* bn_v   = (const float*)d_in[14];
    const float* ggm_w  = (const float*)d_in[15];
    const float* ggm_b  = (const float*)d_in[16];
    const float* qkv_w  = (const float*)d_in[17];
    const float* qkv_b  = (const float*)d_in[18];
    const float* proj_w = (const float*)d_in[19];
    const float* proj_b = (const float*)d_in[20];
    float* out = (float*)d_out;

    // workspace layout (bytes; all 16B-aligned)
    char* ws = (char*)d_ws;
    u16*   y4  = (u16*)(ws);                          // 102,760,448 B
    u16*   dwb = (u16*)(ws + 102760448);              //  51,380,224 B
    u16*   gbf = (u16*)(ws + 154140672);              //  25,690,112 B
    float* G   = (float*)(ws + 179830784);            // 655,360 f32
    float* lgb = G  + 655360;                         // 5,120
    float* F   = lgb + 5120;                          // 655,360
    float* S   = F  + 655360;                         // 5,120
    float* aw  = S  + 5120;                           // 5,120
    float* bo  = aw + 5120;                           // 128
    // Gpart reuses the dwb region (dead after csc_mfma): 16*40*16384*4 = 41.9 MB
    float* Gpart = (float*)(ws + 102760448);

    dw_conv<0><<<dim3(49, 16, 8), 256, 0, stream>>>(x, dw_w0, dw_b0, dwb);
    dw_conv<1><<<dim3(49, 16, 8), 256, 0, stream>>>(x, dw_w1, dw_b1, dwb);
    dw_conv<2><<<dim3(49, 16, 8), 256, 0, stream>>>(x, dw_w2, dw_b2, dwb);
    dw_conv<3><<<dim3(49, 16, 8), 256, 0, stream>>>(x, dw_w3, dw_b3, dwb);

    csc_mfma<<<dim3(392, 1, 8), 256, 0, stream>>>(csc_w, csc_b, dwb, y4);

    ggm_kernel<<<dim3(7, 128, 8), 256, 0, stream>>>(
        y4, bn_g, bn_b, bn_m, bn_v, ggm_w, ggm_b, gbf);

    G_mfma<<<dim3(16, 5, 8), 256, 0, stream>>>(gbf, y4, Gpart);
    G_reduce<<<dim3(40, 16), 256, 0, stream>>>(Gpart, G);

    S_kernel<<<dim3(1024), 256, 0, stream>>>(gbf, y4, S);

    fused_logits_kernel<<<dim3(5, 8), 256, 0, stream>>>(G, S, qkv_w, qkv_b, lgb);

    softmax5_kernel<<<dim3(8), 128, 0, stream>>>(lgb, aw);

    F_kernel<<<dim3(64, 5, 8), 256, 0, stream>>>(proj_w, qkv_w, aw, F);
    bias_kernel<<<dim3(1), 128, 0, stream>>>(proj_w, proj_b, qkv_b, bo);

    final_mfma<<<dim3(98, 1, 8), 256, 0, stream>>>(F, gbf, y4, bo, out);
}

// Round 5
// 615.420 us; speedup vs baseline: 1.1857x; 1.0179x over previous
//
#include <hip/hip_runtime.h>

#define BB 8
#define CIN 64
#define CO 128
#define Hdim 224
#define Wdim 224
#define HWt (224*224)
#define HO 112
#define WO 112
#define Lt (112*112)

typedef unsigned short u16;
typedef short bf16x8 __attribute__((ext_vector_type(8)));
typedef float f32x4  __attribute__((ext_vector_type(4)));
#define MFMA16(a,b,c) __builtin_amdgcn_mfma_f32_16x16x32_bf16((a),(b),(c),0,0,0)

__device__ inline u16 f2bf(float f) {
    union { float f; unsigned u; } v; v.f = f;
    unsigned r = (v.u + 0x7fffu + ((v.u >> 16) & 1u)) >> 16;
    return (u16)r;
}
__device__ inline float bf2f(u16 h) {
    union { unsigned u; float f; } v; v.u = ((unsigned)h) << 16; return v.f;
}
__device__ inline float uasf(unsigned u) {
    union { unsigned u; float f; } v; v.u = u; return v.f;
}

// exact-GELU via Abramowitz-Stegun 7.1.26 erf (max |err| 1.5e-7), ~18 VALU ops
__device__ inline float gelu_fast(float x) {
    float z  = x * 0.7071067811865476f;
    float az = fabsf(z);
    float t  = __builtin_amdgcn_rcpf(fmaf(0.3275911f, az, 1.0f));
    float p  = fmaf(fmaf(fmaf(fmaf(1.061405429f, t, -1.453152027f), t,
                    1.421413741f), t, -0.284496736f), t, 0.254829592f);
    float e  = __expf(-z * z);
    float er = copysignf(1.0f - p * t * e, z);
    return 0.5f * x * (1.0f + er);
}

// ---------------------------------------------------------------------------
// K0: zero the S buffer (5120 floats)
// ---------------------------------------------------------------------------
__global__ void zeroS_kernel(float* __restrict__ S) {
    int i = blockIdx.x * 256 + threadIdx.x;
    if (i < 5120) S[i] = 0.f;
}

// ---------------------------------------------------------------------------
// K1: head-specialized depthwise conv (compile-time k) + channel shuffle.
// ---------------------------------------------------------------------------
template<int HEAD>
__global__ __launch_bounds__(256) void dw_conv(
    const float* __restrict__ x, const float* __restrict__ w,
    const float* __restrict__ bias, u16* __restrict__ dwb)
{
    constexpr int K   = 3 + 2*HEAD;
    constexpr int PAD = HEAD + 1;
    constexpr int R   = 32 + 2*PAD;
    const int tile = blockIdx.x;          // 49
    const int c    = blockIdx.y;          // 16
    const int b    = blockIdx.z;          // 8
    const int th = (tile/7)*32, tw = (tile%7)*32;
    __shared__ float patch[R*40];
    const int tid = threadIdx.x;
    const float* xin = x + (size_t)(b*CIN + HEAD*16 + c)*HWt;
    for (int idx = tid; idx < R*40; idx += 256) {
        int r = idx / 40, cc = idx - r*40;
        int gy = th - PAD + r, gx = tw - 4 + cc;
        float v = 0.f;
        if (gy >= 0 && gy < Hdim && gx >= 0 && gx < Wdim) v = xin[gy*Wdim + gx];
        patch[idx] = v;
    }
    float wreg[K*K];
    const float* wp = w + c*K*K;
    #pragma unroll
    for (int i = 0; i < K*K; i++) wreg[i] = wp[i];
    const float bv = bias[c];
    __syncthreads();

    const int ty = tid >> 3, x0 = (tid & 7) * 4;
    float acc[4] = {bv, bv, bv, bv};
    #pragma unroll
    for (int ky = 0; ky < K; ky++) {
        float rr[12];
        *(float4*)&rr[0] = *(const float4*)&patch[(ty+ky)*40 + x0];
        *(float4*)&rr[4] = *(const float4*)&patch[(ty+ky)*40 + x0 + 4];
        *(float4*)&rr[8] = *(const float4*)&patch[(ty+ky)*40 + x0 + 8];
        #pragma unroll
        for (int kx = 0; kx < K; kx++) {
            const float wv = wreg[ky*K + kx];
            #pragma unroll
            for (int j = 0; j < 4; j++)
                acc[j] = fmaf(rr[j + kx + 4 - PAD], wv, acc[j]);
        }
    }
    const int s = c*4 + HEAD;
    u16 o4[4] = {f2bf(acc[0]), f2bf(acc[1]), f2bf(acc[2]), f2bf(acc[3])};
    *(uint2*)&dwb[(size_t)(b*CIN + s)*HWt + (th+ty)*Wdim + tw + x0] = *(uint2*)o4;
}

// ---------------------------------------------------------------------------
// K2: csc 1x1 via MFMA -> y4 space-to-depth parity layout
// ---------------------------------------------------------------------------
__global__ __launch_bounds__(256) void csc_mfma(
    const float* __restrict__ W, const float* __restrict__ bias,
    const u16* __restrict__ dwb, u16* __restrict__ y4)
{
    const int b  = blockIdx.z;
    const int p0 = blockIdx.x * 128;
    __shared__ u16 Abuf[128*72];
    __shared__ u16 Tbuf[32*132];
    const int tid = threadIdx.x;
    const int wv = tid >> 6, ln = tid & 63;
    const int mh = (wv >> 1)*64, nh = (wv & 1)*64;
    const int lm = ln & 15, kq = ln >> 4;
    for (int t = tid; t < 1024; t += 256) {
        int r = t >> 3, kk = (t & 7)*8;
        const float* src = &W[r*64 + kk];
        float4 f0 = *(const float4*)src, f1 = *(const float4*)(src+4);
        u16 tmp[8] = {f2bf(f0.x),f2bf(f0.y),f2bf(f0.z),f2bf(f0.w),
                      f2bf(f1.x),f2bf(f1.y),f2bf(f1.z),f2bf(f1.w)};
        *(uint4*)&Abuf[r*72 + kk] = *(uint4*)tmp;
    }
    const u16* Db = dwb + (size_t)b*CIN*HWt;
    f32x4 acc[4][4];
    #pragma unroll
    for (int i=0;i<4;i++)
        #pragma unroll
        for (int j=0;j<4;j++) acc[i][j] = (f32x4){0.f,0.f,0.f,0.f};

    for (int kc = 0; kc < 64; kc += 32) {
        __syncthreads();
        for (int t = tid; t < 512; t += 256) {
            int k = t >> 4, n0 = (t & 15)*8;
            *(uint4*)&Tbuf[k*132 + n0] = *(const uint4*)&Db[(size_t)(kc+k)*HWt + p0 + n0];
        }
        __syncthreads();
        bf16x8 af[4], bfr[4];
        #pragma unroll
        for (int tm=0;tm<4;tm++)
            af[tm] = *(bf16x8*)&Abuf[(mh + tm*16 + lm)*72 + kc + kq*8];
        #pragma unroll
        for (int tn=0;tn<4;tn++) {
            int n = nh + tn*16 + lm;
            #pragma unroll
            for (int j=0;j<8;j++) bfr[tn][j] = (short)Tbuf[(kq*8+j)*132 + n];
        }
        #pragma unroll
        for (int tm=0;tm<4;tm++)
            #pragma unroll
            for (int tn=0;tn<4;tn++)
                acc[tm][tn] = MFMA16(af[tm], bfr[tn], acc[tm][tn]);
    }
    #pragma unroll
    for (int tm=0;tm<4;tm++) {
        #pragma unroll
        for (int r=0;r<4;r++) {
            int o = mh + tm*16 + kq*4 + r;
            float bb = bias[o];
            #pragma unroll
            for (int tn=0;tn<4;tn++) {
                int p = p0 + nh + tn*16 + lm;
                int gy = p / 224, gx = p - gy*224;
                int w = (gy&1)*2 + (gx&1);
                y4[((size_t)(b*CO + o)*4 + w)*Lt + (gy>>1)*WO + (gx>>1)]
                    = f2bf(acc[tm][tn][r] + bb);
            }
        }
    }
}

// ---------------------------------------------------------------------------
// K3: BN(eval) -> exact GELU -> dw conv k=7 s=2  (y4 -> gbf), fused S sums.
// 8-out-row tile (21 input rows), LDS 20.2 KB -> ~7 blocks/CU. Linear
// conflict-free staging; conv thread = 2 rows x 2 cols reading 9 rows x 3
// b128 (consecutive lanes -> consecutive 16B blocks). Fused: S partial sums
// (raw y4 planes on owned rows + g-token outputs) -> 5 atomicAdds into S.
// ---------------------------------------------------------------------------
__global__ __launch_bounds__(256) void ggm_kernel(const u16* __restrict__ y4,
    const float* __restrict__ gamma, const float* __restrict__ beta,
    const float* __restrict__ mean, const float* __restrict__ var,
    const float* __restrict__ gw, const float* __restrict__ gb,
    u16* __restrict__ gbf, float* __restrict__ S)
{
    const int ho0 = blockIdx.x * 8;       // 14 tiles, exact
    const int c   = blockIdx.y;           // 128
    const int b   = blockIdx.z;           // 8
    // patch rows r=0..20 <-> gy = 2*ho0-3+r ; row = 60 blocks (240 floats),
    // block j covers gx = 4j-8..4j-5 (j 0,1,58,59 are zero pads).
    __shared__ float patch[21*240];
    __shared__ float sred[4][5];
    const int tid = threadIdx.x;

    const float inv = gamma[c] * rsqrtf(var[c] + 1e-5f);
    const float bsh = fmaf(-mean[c], inv, beta[c]);
    const u16* ybc = y4 + (size_t)(b*CO + c)*4*Lt;

    float wk[49];
    const float* wp = gw + c*49;
    #pragma unroll
    for (int i = 0; i < 49; i++) wk[i] = wp[i];
    const float bv = gb[c];

    // ---- stage + raw plane partial sums on owned rows (r in [3,18]) ----
    float sA[4] = {0.f, 0.f, 0.f, 0.f};   // [(gy&1)*2 + gx-parity]
    for (int idx = tid; idx < 21*60; idx += 256) {
        int r = idx / 60, j = idx - r*60;
        int gy = 2*ho0 - 3 + r;
        float4 v = make_float4(0.f, 0.f, 0.f, 0.f);
        if (gy >= 0 && gy < Hdim && j >= 2 && j <= 57) {
            const u16* pe = ybc + (size_t)((gy&1)*2)*Lt + (gy>>1)*WO + (2*j - 4);
            unsigned e = *(const unsigned*)pe;        // even-gx pair
            unsigned o = *(const unsigned*)(pe + Lt); // odd-gx pair
            float e0 = uasf(e << 16), e1 = uasf(e & 0xffff0000u);
            float o0 = uasf(o << 16), o1 = uasf(o & 0xffff0000u);
            if (r >= 3 && r <= 18) {                  // owned gy rows
                const int rp = (gy & 1)*2;
                sA[rp]     += e0 + e1;
                sA[rp + 1] += o0 + o1;
            }
            v.x = gelu_fast(fmaf(e0, inv, bsh));
            v.y = gelu_fast(fmaf(o0, inv, bsh));
            v.z = gelu_fast(fmaf(e1, inv, bsh));
            v.w = gelu_fast(fmaf(o1, inv, bsh));
        }
        *(float4*)&patch[idx*4] = v;
    }
    __syncthreads();

    // ---- conv: thread -> 2 out-rows x 2 out-cols ----
    float gsum = 0.f;
    if (tid < 224) {
        const int n = tid % 56;           // col pair: wo = 2n, 2n+1
        const int g = tid / 56;           // row pair: ho = ho0 + 2g + i
        float acc[2][2] = {{bv, bv}, {bv, bv}};
        #pragma unroll
        for (int rr = 0; rr < 9; rr++) {
            const float* row = &patch[(4*g + rr)*240 + 4*n + 4];
            float f[12];
            *(float4*)&f[0] = *(const float4*)&row[0];
            *(float4*)&f[4] = *(const float4*)&row[4];
            *(float4*)&f[8] = *(const float4*)&row[8];
            #pragma unroll
            for (int i = 0; i < 2; i++) {
                const int ky = rr - 2*i;
                if (ky >= 0 && ky <= 6) {
                    #pragma unroll
                    for (int kx = 0; kx < 7; kx++) {
                        const float wv = wk[ky*7 + kx];
                        acc[i][0] = fmaf(f[kx + 1], wv, acc[i][0]);
                        acc[i][1] = fmaf(f[kx + 3], wv, acc[i][1]);
                    }
                }
            }
        }
        u16* gout = gbf + (size_t)(b*CO + c)*Lt;
        #pragma unroll
        for (int i = 0; i < 2; i++) {
            u16 o2[2] = {f2bf(acc[i][0]), f2bf(acc[i][1])};
            *(unsigned*)&gout[(ho0 + 2*g + i)*WO + 2*n] = *(unsigned*)o2;
        }
        gsum = acc[0][0] + acc[0][1] + acc[1][0] + acc[1][1];
    }

    // ---- block reduction of 5 partials -> atomicAdd into S ----
    float red[5] = {gsum, sA[0], sA[1], sA[2], sA[3]};
    #pragma unroll
    for (int off = 32; off > 0; off >>= 1) {
        #pragma unroll
        for (int q = 0; q < 5; q++) red[q] += __shfl_down(red[q], off);
    }
    const int wid = tid >> 6, lane = tid & 63;
    if (lane == 0) {
        #pragma unroll
        for (int q = 0; q < 5; q++) sred[wid][q] = red[q];
    }
    __syncthreads();
    if (tid < 5) {
        atomicAdd(&S[((size_t)b*5 + tid)*CO + c],
                  sred[0][tid] + sred[1][tid] + sred[2][tid] + sred[3][tid]);
    }
}

// ---------------------------------------------------------------------------
// K4: G partials via MFMA, BK=64, split-K=16, NO atomics (plain stores).
// Gpart[(split*40 + b*5 + p)][c2][c']
// ---------------------------------------------------------------------------
__global__ __launch_bounds__(256) void G_mfma(
    const u16* __restrict__ gbf, const u16* __restrict__ y4,
    float* __restrict__ Gpart)
{
    const int b = blockIdx.z, p = blockIdx.y, split = blockIdx.x;  // (16,5,8)
    const u16* Ab = gbf + (size_t)b*CO*Lt;
    const u16* Bb; int brs;
    if (p == 0) { Bb = Ab; brs = Lt; }
    else        { Bb = y4 + ((size_t)b*CO*4 + (p-1))*Lt; brs = 4*Lt; }
    __shared__ u16 Abuf[128*72];
    __shared__ u16 Bbuf[128*72];
    const int tid = threadIdx.x;
    const int wv = tid >> 6, ln = tid & 63;
    const int mh = (wv >> 1)*64, nh = (wv & 1)*64;
    const int lm = ln & 15, kq = ln >> 4;
    f32x4 acc[4][4];
    #pragma unroll
    for (int i=0;i<4;i++)
        #pragma unroll
        for (int j=0;j<4;j++) acc[i][j] = (f32x4){0.f,0.f,0.f,0.f};

    for (int ci = split; ci < 196; ci += 16) {   // 196 chunks of BK=64
        const int l0 = ci*64;
        __syncthreads();
        for (int t = tid; t < 1024; t += 256) {
            int r = t >> 3, kk = (t & 7)*8;
            *(uint4*)&Abuf[r*72 + kk] = *(const uint4*)&Ab[(size_t)r*Lt  + l0 + kk];
            *(uint4*)&Bbuf[r*72 + kk] = *(const uint4*)&Bb[(size_t)r*brs + l0 + kk];
        }
        __syncthreads();
        #pragma unroll
        for (int ks = 0; ks < 2; ks++) {
            bf16x8 af[4], bfr[4];
            #pragma unroll
            for (int tm=0;tm<4;tm++)
                af[tm]  = *(bf16x8*)&Abuf[(mh + tm*16 + lm)*72 + ks*32 + kq*8];
            #pragma unroll
            for (int tn=0;tn<4;tn++)
                bfr[tn] = *(bf16x8*)&Bbuf[(nh + tn*16 + lm)*72 + ks*32 + kq*8];
            #pragma unroll
            for (int tm=0;tm<4;tm++)
                #pragma unroll
                for (int tn=0;tn<4;tn++)
                    acc[tm][tn] = MFMA16(af[tm], bfr[tn], acc[tm][tn]);
        }
    }
    float* Go = Gpart + ((size_t)(split*40) + b*5 + p)*CO*CO;
    #pragma unroll
    for (int tm=0;tm<4;tm++)
        #pragma unroll
        for (int r=0;r<4;r++) {
            int mrow = mh + tm*16 + kq*4 + r;
            #pragma unroll
            for (int tn=0;tn<4;tn++)
                Go[mrow*CO + nh + tn*16 + lm] = acc[tm][tn][r];
        }
}

// ---------------------------------------------------------------------------
// K4b: G[bp] = sum over 16 splits of Gpart  (grid (40,16) x 256, float4/thr)
// ---------------------------------------------------------------------------
__global__ void G_reduce(const float* __restrict__ Gpart, float* __restrict__ G)
{
    const int bp = blockIdx.x;
    const int i4 = (blockIdx.y*256 + threadIdx.x)*4;   // < 16384
    float4 s = make_float4(0.f, 0.f, 0.f, 0.f);
    #pragma unroll
    for (int sp = 0; sp < 16; sp++) {
        float4 v = *(const float4*)&Gpart[((size_t)(sp*40) + bp)*CO*CO + i4];
        s.x += v.x; s.y += v.y; s.z += v.z; s.w += v.w;
    }
    *(float4*)&G[(size_t)bp*CO*CO + i4] = s;
}

// ---------------------------------------------------------------------------
// K6: fused KG+logits per (b,p).
// ---------------------------------------------------------------------------
__global__ __launch_bounds__(256) void fused_logits_kernel(
    const float* __restrict__ G, const float* __restrict__ S,
    const float* __restrict__ qkv_w, const float* __restrict__ qkv_b,
    float* __restrict__ lg)
{
    const int p = blockIdx.x, b = blockIdx.y;   // grid (5,8)
    __shared__ float Wl[32*132];                // G chunk, transposed [kk][c2]
    __shared__ float Al[32*132];                // kw^T chunk [kk][c]
    __shared__ float KGl[128*128];              // KG[c2][c]
    const int tid = threadIdx.x;
    const int og = (tid >> 4) * 8;              // c2 tile
    const int pg = (tid & 15) * 8;              // c tile
    const float* Gp = G + (size_t)(b*5 + p)*CO*CO;
    float acc[8][8];
    #pragma unroll
    for (int i=0;i<8;i++)
        #pragma unroll
        for (int j=0;j<8;j++) acc[i][j]=0.f;

    for (int kc = 0; kc < 128; kc += 32) {
        __syncthreads();
        for (int t = tid; t < 4096; t += 256) {
            int kk = t & 31, o = t >> 5;
            Wl[kk*132 + o] = Gp[(size_t)o*CO + kc + kk];          // G[c2][cp]
            Al[kk*132 + o] = qkv_w[(size_t)(CO + o)*CO + kc + kk]; // kw[c][cp]
        }
        __syncthreads();
        #pragma unroll 4
        for (int kk = 0; kk < 32; kk++) {
            float wv[8], av[8];
            *(float4*)&wv[0] = *(const float4*)&Wl[kk*132+og];
            *(float4*)&wv[4] = *(const float4*)&Wl[kk*132+og+4];
            *(float4*)&av[0] = *(const float4*)&Al[kk*132+pg];
            *(float4*)&av[4] = *(const float4*)&Al[kk*132+pg+4];
            #pragma unroll
            for (int i=0;i<8;i++)
                #pragma unroll
                for (int j=0;j<8;j++)
                    acc[i][j] = fmaf(wv[i], av[j], acc[i][j]);
        }
    }
    #pragma unroll
    for (int i=0;i<8;i++) {
        #pragma unroll
        for (int j=0;j<8;j+=4)
            *(float4*)&KGl[(og+i)*128 + pg + j] = *(float4*)&acc[i][j];
    }
    __syncthreads();
    if (tid < 128) {
        const int c = tid;
        const float qb = qkv_b[c], kb = qkv_b[CO + c];
        const float* S0 = S + (size_t)b*5*CO;        // g-token sums
        const float* Sp = S0 + p*CO;                 // token-p sums
        const float* qwrow = qkv_w + (size_t)c*CO;
        const float* kwrow = qkv_w + (size_t)(CO + c)*CO;
        float sq = qb * 12544.f, ks = 0.f, s = 0.f;
        for (int c2 = 0; c2 < CO; c2++) {
            sq = fmaf(qwrow[c2], S0[c2], sq);
            ks = fmaf(kwrow[c2], Sp[c2], ks);
            s  = fmaf(qwrow[c2], KGl[c2*128 + c], s);
        }
        lg[(size_t)(b*5 + p)*CO + c] = s + qb*ks + kb*sq;
    }
}

// ---------------------------------------------------------------------------
// K7: 5-way softmax over p -> a[b,c,p]
// ---------------------------------------------------------------------------
__global__ void softmax5_kernel(const float* __restrict__ lg, float* __restrict__ a)
{
    const int b = blockIdx.x, c = threadIdx.x;  // grid 8 x 128
    float v[5];
    #pragma unroll
    for (int p=0;p<5;p++) v[p] = lg[(size_t)(b*5 + p)*CO + c];
    const float scl = 0.08838834764831845f; // 1/sqrt(128)
    float mx = v[0];
    #pragma unroll
    for (int p=1;p<5;p++) mx = fmaxf(mx, v[p]);
    float e[5], sum = 0.f;
    #pragma unroll
    for (int p=0;p<5;p++){ e[p] = __expf((v[p]-mx)*scl); sum += e[p]; }
    const float rs = 1.f/sum;
    #pragma unroll
    for (int p=0;p<5;p++) a[((size_t)b*CO + c)*5 + p] = e[p]*rs;
}

// ---------------------------------------------------------------------------
// K8: F_p[b,o,c'] = sum_c proj_w[o,c]*a[b,c,p]*Vw[c,c']   (fp32)
// ---------------------------------------------------------------------------
__global__ void F_kernel(const float* __restrict__ proj_w,
    const float* __restrict__ qkv_w, const float* __restrict__ a,
    float* __restrict__ F)
{
    const int b = blockIdx.z, p = blockIdx.y;   // (64,5,8) x 256
    const int o  = blockIdx.x*2 + (threadIdx.x>>7);
    const int cp = threadIdx.x & 127;
    const float* vw = qkv_w + 2*CO*CO;
    float s = 0.f;
    for (int c=0;c<CO;c++)
        s = fmaf(proj_w[o*CO+c] * a[((size_t)b*CO+c)*5 + p], vw[c*CO+cp], s);
    F[(((size_t)(b*5+p))*CO + o)*CO + cp] = s;
}

// ---------------------------------------------------------------------------
// K9: biasout[o] = proj_b[o] + sum_c proj_w[o,c]*vb[c]
// ---------------------------------------------------------------------------
__global__ void bias_kernel(const float* __restrict__ proj_w,
    const float* __restrict__ proj_b, const float* __restrict__ qkv_b,
    float* __restrict__ biasout)
{
    const int o = threadIdx.x; // 128
    const float* vb = qkv_b + 2*CO;
    float s = proj_b[o];
    for (int c=0;c<CO;c++) s = fmaf(proj_w[o*CO+c], vb[c], s);
    biasout[o] = s;
}

// ---------------------------------------------------------------------------
// K10: out[b,o,l] = sum_p F_p[o,:]·tok_p[:,l] + biasout[o]  via MFMA
// ---------------------------------------------------------------------------
__global__ __launch_bounds__(256) void final_mfma(
    const float* __restrict__ F, const u16* __restrict__ gbf,
    const u16* __restrict__ y4, const float* __restrict__ biasout,
    float* __restrict__ out)
{
    const int b = blockIdx.z;
    const int p0 = blockIdx.x * 128;
    __shared__ u16 Abuf[128*40];
    __shared__ u16 Tbuf[32*132];
    const int tid = threadIdx.x;
    const int wv = tid >> 6, ln = tid & 63;
    const int mh = (wv >> 1)*64, nh = (wv & 1)*64;
    const int lm = ln & 15, kq = ln >> 4;
    f32x4 acc[4][4];
    #pragma unroll
    for (int i=0;i<4;i++)
        #pragma unroll
        for (int j=0;j<4;j++) acc[i][j] = (f32x4){0.f,0.f,0.f,0.f};

    for (int ph = 0; ph < 5; ph++) {
        const float* Fp = F + (size_t)(b*5 + ph)*CO*CO;
        const u16* Bb; int brs;
        if (ph == 0) { Bb = gbf + (size_t)b*CO*Lt; brs = Lt; }
        else         { Bb = y4 + ((size_t)b*CO*4 + (ph-1))*Lt; brs = 4*Lt; }
        for (int kc = 0; kc < CO; kc += 32) {
            __syncthreads();
            for (int t = tid; t < 512; t += 256) {
                int r = t >> 2, kk = (t & 3)*8;
                const float* src = &Fp[r*CO + kc + kk];
                float4 f0 = *(const float4*)src, f1 = *(const float4*)(src+4);
                u16 tmp[8] = {f2bf(f0.x),f2bf(f0.y),f2bf(f0.z),f2bf(f0.w),
                              f2bf(f1.x),f2bf(f1.y),f2bf(f1.z),f2bf(f1.w)};
                *(uint4*)&Abuf[r*40 + kk] = *(uint4*)tmp;
            }
            for (int t = tid; t < 512; t += 256) {
                int k = t >> 4, n0 = (t & 15)*8;
                *(uint4*)&Tbuf[k*132 + n0] = *(const uint4*)&Bb[(size_t)(kc+k)*brs + p0 + n0];
            }
            __syncthreads();
            bf16x8 af[4], bfr[4];
            #pragma unroll
            for (int tm=0;tm<4;tm++)
                af[tm] = *(bf16x8*)&Abuf[(mh + tm*16 + lm)*40 + kq*8];
            #pragma unroll
            for (int tn=0;tn<4;tn++) {
                int n = nh + tn*16 + lm;
                #pragma unroll
                for (int j=0;j<8;j++) bfr[tn][j] = (short)Tbuf[(kq*8+j)*132 + n];
            }
            #pragma unroll
            for (int tm=0;tm<4;tm++)
                #pragma unroll
                for (int tn=0;tn<4;tn++)
                    acc[tm][tn] = MFMA16(af[tm], bfr[tn], acc[tm][tn]);
        }
    }
    float* Ob = out + (size_t)b*CO*Lt;
    #pragma unroll
    for (int tm=0;tm<4;tm++) {
        #pragma unroll
        for (int r=0;r<4;r++) {
            int o = mh + tm*16 + kq*4 + r;
            float bb = biasout[o];
            #pragma unroll
            for (int tn=0;tn<4;tn++)
                Ob[(size_t)o*Lt + p0 + nh + tn*16 + lm] = acc[tm][tn][r] + bb;
        }
    }
}

// ---------------------------------------------------------------------------
extern "C" void kernel_launch(void* const* d_in, const int* in_sizes, int n_in,
                              void* d_out, int out_size, void* d_ws, size_t ws_size,
                              hipStream_t stream) {
    const float* x      = (const float*)d_in[0];
    const float* dw_w0  = (const float*)d_in[1];
    const float* dw_b0  = (const float*)d_in[2];
    const float* dw_w1  = (const float*)d_in[3];
    const float* dw_b1  = (const float*)d_in[4];
    const float* dw_w2  = (const float*)d_in[5];
    const float* dw_b2  = (const float*)d_in[6];
    const float* dw_w3  = (const float*)d_in[7];
    const float* dw_b3  = (const float*)d_in[8];
    const float* csc_w  = (const float*)d_in[9];
    const float* csc_b  = (const float*)d_in[10];
    const float* bn_g   = (const float*)d_in[11];
    const float* bn_b   = (const float*)d_in[12];
    const float* bn_m   = (const float*)d_in[13];
    const float* bn_v   = (const float*)d_in[14];
    const float* ggm_w  = (const float*)d_in[15];
    const float* ggm_b  = (const float*)d_in[16];
    const float* qkv_w  = (const float*)d_in[17];
    const float* qkv_b  = (const float*)d_in[18];
    const float* proj_w = (const float*)d_in[19];
    const float* proj_b = (const float*)d_in[20];
    float* out = (float*)d_out;

    // workspace layout (bytes; all 16B-aligned)
    char* ws = (char*)d_ws;
    u16*   y4  = (u16*)(ws);                          // 102,760,448 B
    u16*   dwb = (u16*)(ws + 102760448);              //  51,380,224 B
    u16*   gbf = (u16*)(ws + 154140672);              //  25,690,112 B
    float* G   = (float*)(ws + 179830784);            // 655,360 f32
    float* lgb = G  + 655360;                         // 5,120
    float* F   = lgb + 5120;                          // 655,360
    float* S   = F  + 655360;                         // 5,120
    float* aw  = S  + 5120;                           // 5,120
    float* bo  = aw + 5120;                           // 128
    // Gpart reuses the dwb region (dead after csc_mfma): 16*40*16384*4 = 41.9 MB
    float* Gpart = (float*)(ws + 102760448);

    zeroS_kernel<<<dim3(20), 256, 0, stream>>>(S);

    dw_conv<0><<<dim3(49, 16, 8), 256, 0, stream>>>(x, dw_w0, dw_b0, dwb);
    dw_conv<1><<<dim3(49, 16, 8), 256, 0, stream>>>(x, dw_w1, dw_b1, dwb);
    dw_conv<2><<<dim3(49, 16, 8), 256, 0, stream>>>(x, dw_w2, dw_b2, dwb);
    dw_conv<3><<<dim3(49, 16, 8), 256, 0, stream>>>(x, dw_w3, dw_b3, dwb);

    csc_mfma<<<dim3(392, 1, 8), 256, 0, stream>>>(csc_w, csc_b, dwb, y4);

    ggm_kernel<<<dim3(14, 128, 8), 256, 0, stream>>>(
        y4, bn_g, bn_b, bn_m, bn_v, ggm_w, ggm_b, gbf, S);

    G_mfma<<<dim3(16, 5, 8), 256, 0, stream>>>(gbf, y4, Gpart);
    G_reduce<<<dim3(40, 16), 256, 0, stream>>>(Gpart, G);

    fused_logits_kernel<<<dim3(5, 8), 256, 0, stream>>>(G, S, qkv_w, qkv_b, lgb);

    softmax5_kernel<<<dim3(8), 128, 0, stream>>>(lgb, aw);

    F_kernel<<<dim3(64, 5, 8), 256, 0, stream>>>(proj_w, qkv_w, aw, F);
    bias_kernel<<<dim3(1), 128, 0, stream>>>(proj_w, proj_b, qkv_b, bo);

    final_mfma<<<dim3(98, 1, 8), 256, 0, stream>>>(F, gbf, y4, bo, out);
}